// Round 20
// baseline (76.907 us; speedup 1.0000x reference)
//
#include <hip/hip_runtime.h>
#include <math.h>

#define EPS 1e-5f

typedef __attribute__((ext_vector_type(8))) short short8v;
typedef __attribute__((ext_vector_type(4))) float f32x4;
typedef __attribute__((ext_vector_type(16))) float f32x16;

// ---- bf16 split helpers (RNE) ----
__device__ __forceinline__ unsigned short bf16r(float x) {
    unsigned u = __float_as_uint(x);
    return (unsigned short)((u + 0x7FFFu + ((u >> 16) & 1u)) >> 16);
}
__device__ __forceinline__ float bf2f(unsigned short h) {
    return __uint_as_float(((unsigned)h) << 16);
}
__device__ __forceinline__ unsigned packhl(float x) {
    const unsigned short h = bf16r(x);
    const unsigned short l = bf16r(x - bf2f(h));
    return (unsigned)h | ((unsigned)l << 16);
}

// ---------------------------------------------------------------------------
// k_pre (66 blocks): Bpack (conv3 bf16-split B), w2q/bias2, Bedge32, qTab4,
// bias3, sf1/cf1, sf2/cf2.  (R17/R19-validated)
// ---------------------------------------------------------------------------
__global__ __launch_bounds__(256) void k_pre(
    const float* __restrict__ w3, const float* __restrict__ b3,
    const float* __restrict__ g3, const float* __restrict__ be3,
    const float* __restrict__ m3, const float* __restrict__ v3,
    const float* __restrict__ w2, const float* __restrict__ b2,
    const float* __restrict__ g2, const float* __restrict__ be2,
    const float* __restrict__ m2, const float* __restrict__ v2,
    const float* __restrict__ w_info, const float* __restrict__ b_info,
    const float* __restrict__ g_info, const float* __restrict__ be_info,
    const float* __restrict__ m_info, const float* __restrict__ v_info,
    const float* __restrict__ bf1, const float* __restrict__ gf1,
    const float* __restrict__ bef1, const float* __restrict__ mf1,
    const float* __restrict__ vf1,
    const float* __restrict__ bf2, const float* __restrict__ gf2,
    const float* __restrict__ bef2, const float* __restrict__ mf2,
    const float* __restrict__ vf2,
    unsigned short* __restrict__ Bh, unsigned short* __restrict__ Bl,
    float* __restrict__ bias3,
    float4* __restrict__ w2q, float* __restrict__ bias2,
    unsigned short* __restrict__ Bedge,   // [2][64][8] bf16 (32x32 frags)
    float4* __restrict__ qTab4,
    float* __restrict__ sf1, float* __restrict__ cf1,
    float* __restrict__ sf2, float* __restrict__ cf2)
{
    const int blk = blockIdx.x, tid = threadIdx.x;
    if (blk < 64) {
        const int t = blk * 256 + tid;        // (kt,nt,lane)
        const int kt = t >> 12;
        const int nt = (t >> 6) & 63;
        const int lane = t & 63;
        const int o  = nt * 16 + (lane & 15);
        const int kb = kt * 32 + ((lane >> 4) << 3);
        const float a3 = g3[o] * rsqrtf(v3[o] + EPS);
        unsigned short hi[8], lo[8];
        #pragma unroll
        for (int j = 0; j < 8; ++j) {
            const float wv = a3 * w3[(size_t)o * 128 + kb + j];
            hi[j] = bf16r(wv);
            lo[j] = bf16r(wv - bf2f(hi[j]));
        }
        #pragma unroll
        for (int j = 0; j < 8; ++j) {
            Bh[(size_t)t * 8 + j] = hi[j];
            Bl[(size_t)t * 8 + j] = lo[j];
        }
    } else if (blk == 64) {
        for (int idx = tid; idx < 2048; idx += 256) {
            const int o2 = idx & 127, cq = idx >> 7;
            const float a2 = g2[o2] * rsqrtf(v2[o2] + EPS);
            const float4 w = *(const float4*)(w2 + (size_t)o2 * 64 + cq * 4);
            w2q[cq * 128 + o2] = make_float4(a2 * w.x, a2 * w.y, a2 * w.z, a2 * w.w);
        }
        if (tid < 128) {
            const float a2 = g2[tid] * rsqrtf(v2[tid] + EPS);
            bias2[tid] = a2 * (b2[tid] - m2[tid]) + be2[tid];
        }
    } else {
        if (tid < 128) {
            const int nt = tid >> 6, lane = tid & 63;
            const int grp = lane >> 5;
            const int o = nt * 32 + (lane & 31);
            const float a = g_info[o] * rsqrtf(v_info[o] + EPS);
            const float c0 = a * w_info[o*6+0];
            const float c1 = a * w_info[o*6+1];
            const float c2 = a * w_info[o*6+2];
            const unsigned short ch0 = bf16r(c0), ch1 = bf16r(c1), ch2 = bf16r(c2);
            const unsigned short cl0 = bf16r(c0 - bf2f(ch0));
            const unsigned short cl1 = bf16r(c1 - bf2f(ch1));
            const unsigned short cl2 = bf16r(c2 - bf2f(ch2));
            unsigned short out[8] = {0,0,0,0,0,0,0,0};
            if (grp == 0) {
                out[0]=ch0; out[1]=ch1; out[2]=ch2;
                out[3]=cl0; out[4]=cl1; out[5]=cl2;
                out[6]=ch0; out[7]=ch1;
            } else {
                out[0]=ch2;
            }
            #pragma unroll
            for (int j = 0; j < 8; ++j)
                Bedge[(size_t)(nt*64 + lane)*8 + j] = out[j];
        }
        if (tid < 64) {
            const int o = tid;
            const float w0 = w_info[o*6+0], w1 = w_info[o*6+1], w2c = w_info[o*6+2];
            const float w3c = w_info[o*6+3], w4 = w_info[o*6+4], w5 = w_info[o*6+5];
            const float a = g_info[o] * rsqrtf(v_info[o] + EPS);
            qTab4[o] = make_float4(a*(w3c-w0), a*(w4-w1), a*(w5-w2c),
                                   a*(b_info[o]-m_info[o]) + be_info[o]);
        }
        for (int c = tid; c < 1024; c += 256) {
            const float a3 = g3[c] * rsqrtf(v3[c] + EPS);
            bias3[c] = a3 * (b3[c] - m3[c]) + be3[c];
        }
        for (int c = tid; c < 512; c += 256) {
            const float s = gf1[c] * rsqrtf(vf1[c] + EPS);
            sf1[c] = s;
            cf1[c] = s * (bf1[c] - mf1[c]) + bef1[c];
        }
        {
            const int c = tid;
            const float s = gf2[c] * rsqrtf(vf2[c] + EPS);
            sf2[c] = s;
            cf2[c] = s * (bf2[c] - mf2[c]) + bef2[c];
        }
    }
}

// ---------------------------------------------------------------------------
// k_edgehalf: edge-conv 32x32x16 MFMA partial-max over ONE k-half (260 rows).
// Block = (b, half): 512 blocks (2/CU co-resident, 4 waves/SIMD vs R17's 2),
// stages 46.8KB packed bf16, 9 mt per n (vs 17).  Raw column max written to
// gpart[b][half][15][64]; bias+relu deferred to k_mid2 (max-commutes).
// Local rows >259 clamp to 259 (duplicate, max-safe).  VGPR state = R17 (~88).
// ---------------------------------------------------------------------------
__global__ __launch_bounds__(512) void k_edgehalf(
    const float* __restrict__ info,       // [256,520,15,3]
    const unsigned short* __restrict__ Bedge,  // [2][64][8]
    float* __restrict__ gpart)            // [256][2][15][64]
{
    __shared__ unsigned dsb[11700];       // 46800 B  [260][15][3] packed hi|lo

    const int tid = threadIdx.x;
    const int b    = blockIdx.x >> 1;
    const int half = blockIdx.x & 1;

    { // coalesced staging + bf16 hi/lo packing of this half's 260 rows
        const float4* src = (const float4*)(info + (size_t)b * 23400 + half * 11700);
        uint4* dst = (uint4*)dsb;
        for (int i = tid; i < 2925; i += 512) {
            const float4 v = src[i];
            uint4 pv;
            pv.x = packhl(v.x); pv.y = packhl(v.y);
            pv.z = packhl(v.z); pv.w = packhl(v.w);
            dst[i] = pv;
        }
    }
    __syncthreads();

    const int wave = tid >> 6, lane = tid & 63;
    const int la = lane & 31;
    const bool hiHalf = lane >= 32;

    short8v bfrag0 = *(const short8v*)(Bedge + (size_t)(0*64 + lane)*8);
    short8v bfrag1 = *(const short8v*)(Bedge + (size_t)(1*64 + lane)*8);

    const f32x16 zero16 = {0.f,0.f,0.f,0.f,0.f,0.f,0.f,0.f,
                           0.f,0.f,0.f,0.f,0.f,0.f,0.f,0.f};

    for (int n = wave; n < 15; n += 8) {
        float m0 = -INFINITY, m1 = -INFINITY;

        #pragma unroll 1
        for (int mt = 0; mt < 9; ++mt) {
            int row = mt*32 + la;
            row = row > 259 ? 259 : row;          // clamp within half
            const unsigned* p = dsb + row*45 + n*3;
            int4 ai;
            if (!hiHalf) {
                const unsigned w0 = p[0], w1 = p[1], w2 = p[2];
                ai.x = (int)((w0 & 0xFFFFu) | (w1 << 16));        // dh0,dh1
                ai.y = (int)((w2 & 0xFFFFu) | (w0 << 16));        // dh2,dh0
                ai.z = (int)((w1 & 0xFFFFu) | (w2 << 16));        // dh1,dh2
                ai.w = (int)((w0 >> 16) | (w1 & 0xFFFF0000u));    // dl0,dl1
            } else {
                const unsigned w2 = p[2];
                ai.x = (int)(w2 >> 16);                           // dl2
                ai.y = 0; ai.z = 0; ai.w = 0;
            }
            const short8v afrag = *(short8v*)&ai;
            const f32x16 r0 = __builtin_amdgcn_mfma_f32_32x32x16_bf16(afrag, bfrag0, zero16, 0,0,0);
            const f32x16 r1 = __builtin_amdgcn_mfma_f32_32x32x16_bf16(afrag, bfrag1, zero16, 0,0,0);
            #pragma unroll
            for (int c = 0; c < 16; ++c) {
                m0 = fmaxf(m0, r0[c]);
                m1 = fmaxf(m1, r1[c]);
            }
        }
        m0 = fmaxf(m0, __shfl_xor(m0, 32));
        m1 = fmaxf(m1, __shfl_xor(m1, 32));

        if (lane < 32) {
            float* gp = gpart + ((size_t)(b*2 + half)*15 + n) * 64;
            gp[lane]      = m0;       // o = 0..31
            gp[32 + lane] = m1;       // o = 32..63
        }
    }
}

// ---------------------------------------------------------------------------
// k_mid2: combine half maxima + bias + relu -> h1, conv2 (folded) -> h2
// bf16 hi/lo.  One block per b, 256 thr.  (R7-validated combine pattern)
// ---------------------------------------------------------------------------
__global__ __launch_bounds__(256) void k_mid2(
    const float* __restrict__ gpart,  // [256][2][15][64]
    const float* __restrict__ pts,    // [256,15,3]
    const float4* __restrict__ qTab4, // [64]
    const float4* __restrict__ w2q,   // [16][128]
    const float* __restrict__ bias2,  // [128]
    unsigned short* __restrict__ h2h, // [256][16][128]
    unsigned short* __restrict__ h2l) // [256][16][128]
{
    __shared__ float h1s[960];        // [15][64]
    const int tid = threadIdx.x;
    const int b = blockIdx.x;

    const float* gp = gpart + (size_t)b * 1920;
    for (int i = tid; i < 960; i += 256) {
        const int n = i >> 6, o = i & 63;
        const float m = fmaxf(gp[i], gp[960 + i]);
        const float x0 = pts[b*45 + n*3 + 0];
        const float x1 = pts[b*45 + n*3 + 1];
        const float x2 = pts[b*45 + n*3 + 2];
        const float4 qv = qTab4[o];
        const float bias = fmaf(qv.x, x0, fmaf(qv.y, x1, fmaf(qv.z, x2, qv.w)));
        h1s[i] = fmaxf(m + bias, 0.f);
    }
    __syncthreads();

    // conv2: 16x128 outputs (row 15 = pad 0), bf16 hi/lo split write
    for (int idx = tid; idx < 2048; idx += 256) {
        const int o2 = idx & 127, n = idx >> 7;
        float val = 0.f;
        if (n < 15) {
            float acc = 0.f;
            #pragma unroll
            for (int cq = 0; cq < 16; ++cq) {
                const float4 h4 = *(const float4*)(&h1s[n*64 + cq*4]);
                const float4 w4 = w2q[cq*128 + o2];
                acc = fmaf(w4.x, h4.x, fmaf(w4.y, h4.y,
                      fmaf(w4.z, h4.z, fmaf(w4.w, h4.w, acc))));
            }
            val = fmaxf(acc + bias2[o2], 0.f);
        }
        const unsigned short hi = bf16r(val);
        const unsigned short lo = bf16r(val - bf2f(hi));
        h2h[(size_t)b*2048 + n*128 + o2] = hi;
        h2l[(size_t)b*2048 + n*128 + o2] = lo;
    }
}

// ---------------------------------------------------------------------------
// k_s3: conv3 MFMA + global max.  512 thr (R19-validated).
// ---------------------------------------------------------------------------
__global__ __launch_bounds__(512) void k_s3(
    const unsigned short* __restrict__ h2h,
    const unsigned short* __restrict__ h2l,
    const unsigned short* __restrict__ Bh,
    const unsigned short* __restrict__ Bl,
    const float* __restrict__ bias3,
    float* __restrict__ gout)         // [256,1024]
{
    const int tid = threadIdx.x;
    const int b = blockIdx.x;
    const int wave = tid >> 6, lane = tid & 63;
    const int arow = lane & 15, agrp = lane >> 4;

    short8v ahi[4], alo[4];
    {
        const unsigned short* Ab = h2h + (size_t)b*2048 + arow*128 + agrp*8;
        const unsigned short* Al = h2l + (size_t)b*2048 + arow*128 + agrp*8;
        #pragma unroll
        for (int kt = 0; kt < 4; ++kt) {
            ahi[kt] = *(const short8v*)(Ab + kt*32);
            alo[kt] = *(const short8v*)(Al + kt*32);
        }
    }

    for (int ntl = 0; ntl < 8; ++ntl) {
        const int nt = wave * 8 + ntl;
        f32x4 a0 = {0.f, 0.f, 0.f, 0.f};
        f32x4 a1 = a0, a2 = a0;
        #pragma unroll
        for (int kt = 0; kt < 4; ++kt) {
            const size_t off = (((size_t)kt*64 + nt)*64 + lane) * 8;
            const short8v bh = *(const short8v*)(Bh + off);
            const short8v bl = *(const short8v*)(Bl + off);
            a0 = __builtin_amdgcn_mfma_f32_16x16x32_bf16(ahi[kt], bh, a0, 0, 0, 0);
            a1 = __builtin_amdgcn_mfma_f32_16x16x32_bf16(ahi[kt], bl, a1, 0, 0, 0);
            a2 = __builtin_amdgcn_mfma_f32_16x16x32_bf16(alo[kt], bh, a2, 0, 0, 0);
        }
        const float r0 = a0[0] + a1[0] + a2[0];
        const float r1 = a0[1] + a1[1] + a2[1];
        const float r2 = a0[2] + a1[2] + a2[2];
        const float r3 = a0[3] + a1[3] + a2[3];
        float m = fmaxf(fmaxf(r0, r1), r2);
        if (agrp != 3) m = fmaxf(m, r3);          // exclude pad row 15
        m = fmaxf(m, __shfl_xor(m, 16));
        m = fmaxf(m, __shfl_xor(m, 32));
        if (lane < 16)
            gout[(size_t)b*1024 + nt*16 + lane] = m + bias3[nt*16 + lane];
    }
}

// ---------------------------------------------------------------------------
// k_fc1p: fc1 split-K=4 raw partials.  grid (8,16,4).  (R19-validated)
// ---------------------------------------------------------------------------
__global__ __launch_bounds__(256) void k_fc1p(
    const float* __restrict__ A,      // g [256][1024]
    const float* __restrict__ W,      // wf1 [512][1024]
    float* __restrict__ P)            // [4][256][512]
{
    __shared__ float As[32][36];
    __shared__ float Ws[32][36];

    const int tid = threadIdx.x;
    const int bm = blockIdx.x * 32, bn = blockIdx.y * 32;
    const int ks = blockIdx.z;
    const int ml = (tid >> 4) * 2, nl = (tid & 15) * 2;
    const int row = tid >> 3, kq = (tid & 7) * 4;

    float acc00 = 0.f, acc01 = 0.f, acc10 = 0.f, acc11 = 0.f;

    for (int k0 = 0; k0 < 256; k0 += 32) {
        const int ch = ks * 256 + k0 + kq;
        const float4 av = *(const float4*)(A + (size_t)(bm + row) * 1024 + ch);
        const float4 wv = *(const float4*)(W + (size_t)(bn + row) * 1024 + ch);
        __syncthreads();
        *(float4*)(&As[row][kq]) = av;
        *(float4*)(&Ws[row][kq]) = wv;
        __syncthreads();
        const float4* a0p = (const float4*)(&As[ml][0]);
        const float4* a1p = (const float4*)(&As[ml + 1][0]);
        const float4* b0p = (const float4*)(&Ws[nl][0]);
        const float4* b1p = (const float4*)(&Ws[nl + 1][0]);
        #pragma unroll
        for (int q = 0; q < 8; ++q) {
            const float4 a0 = a0p[q], a1 = a1p[q], b0 = b0p[q], b1 = b1p[q];
            acc00 = fmaf(a0.x, b0.x, fmaf(a0.y, b0.y, fmaf(a0.z, b0.z, fmaf(a0.w, b0.w, acc00))));
            acc01 = fmaf(a0.x, b1.x, fmaf(a0.y, b1.y, fmaf(a0.z, b1.z, fmaf(a0.w, b1.w, acc01))));
            acc10 = fmaf(a1.x, b0.x, fmaf(a1.y, b0.y, fmaf(a1.z, b0.z, fmaf(a1.w, b0.w, acc10))));
            acc11 = fmaf(a1.x, b1.x, fmaf(a1.y, b1.y, fmaf(a1.z, b1.z, fmaf(a1.w, b1.w, acc11))));
        }
    }
    float* p0 = P + (size_t)ks * 131072 + (size_t)(bm + ml) * 512 + bn + nl;
    p0[0] = acc00; p0[1] = acc01;
    float* p1 = p0 + 512;
    p1[0] = acc10; p1[1] = acc11;
}

// ---------------------------------------------------------------------------
// k_fc2p: fc2 split-K=4.  A-tile finishes f1 from 4 fp partials.  (R19)
// ---------------------------------------------------------------------------
__global__ __launch_bounds__(256) void k_fc2p(
    const float* __restrict__ fp,     // [4][256][512]
    const float* __restrict__ sf1, const float* __restrict__ cf1,
    const float* __restrict__ W,      // wf2 [256][512]
    float* __restrict__ P2)           // [4][256][256]
{
    __shared__ float As[32][36];
    __shared__ float Ws[32][36];

    const int tid = threadIdx.x;
    const int bm = blockIdx.x * 32, bn = blockIdx.y * 32;
    const int ks = blockIdx.z;
    const int ml = (tid >> 4) * 2, nl = (tid & 15) * 2;
    const int row = tid >> 3, kq = (tid & 7) * 4;

    float acc00 = 0.f, acc01 = 0.f, acc10 = 0.f, acc11 = 0.f;

    for (int k0 = 0; k0 < 128; k0 += 32) {
        const int ch = ks * 128 + k0 + kq;
        const size_t ro = (size_t)(bm + row) * 512 + ch;
        const float4 p0 = *(const float4*)(fp + ro);
        const float4 p1 = *(const float4*)(fp + 131072 + ro);
        const float4 p2 = *(const float4*)(fp + 262144 + ro);
        const float4 p3 = *(const float4*)(fp + 393216 + ro);
        const float4 s4 = *(const float4*)(sf1 + ch);
        const float4 c4 = *(const float4*)(cf1 + ch);
        float4 av;
        av.x = fmaxf(fmaf(s4.x, p0.x + p1.x + p2.x + p3.x, c4.x), 0.f);
        av.y = fmaxf(fmaf(s4.y, p0.y + p1.y + p2.y + p3.y, c4.y), 0.f);
        av.z = fmaxf(fmaf(s4.z, p0.z + p1.z + p2.z + p3.z, c4.z), 0.f);
        av.w = fmaxf(fmaf(s4.w, p0.w + p1.w + p2.w + p3.w, c4.w), 0.f);
        const float4 wv = *(const float4*)(W + (size_t)(bn + row) * 512 + ch);
        __syncthreads();
        *(float4*)(&As[row][kq]) = av;
        *(float4*)(&Ws[row][kq]) = wv;
        __syncthreads();
        const float4* a0p = (const float4*)(&As[ml][0]);
        const float4* a1p = (const float4*)(&As[ml + 1][0]);
        const float4* b0p = (const float4*)(&Ws[nl][0]);
        const float4* b1p = (const float4*)(&Ws[nl + 1][0]);
        #pragma unroll
        for (int q = 0; q < 8; ++q) {
            const float4 a0 = a0p[q], a1 = a1p[q], b0 = b0p[q], b1 = b1p[q];
            acc00 = fmaf(a0.x, b0.x, fmaf(a0.y, b0.y, fmaf(a0.z, b0.z, fmaf(a0.w, b0.w, acc00))));
            acc01 = fmaf(a0.x, b1.x, fmaf(a0.y, b1.y, fmaf(a0.z, b1.z, fmaf(a0.w, b1.w, acc01))));
            acc10 = fmaf(a1.x, b0.x, fmaf(a1.y, b0.y, fmaf(a1.z, b0.z, fmaf(a1.w, b0.w, acc10))));
            acc11 = fmaf(a1.x, b1.x, fmaf(a1.y, b1.y, fmaf(a1.z, b1.z, fmaf(a1.w, b1.w, acc11))));
        }
    }
    float* q0 = P2 + (size_t)ks * 65536 + (size_t)(bm + ml) * 256 + bn + nl;
    q0[0] = acc00; q0[1] = acc01;
    float* q1 = q0 + 256;
    q1[0] = acc10; q1[1] = acc11;
}

// ---------------------------------------------------------------------------
// k_fc3f: fc3 with fused f2 epilogue.  (R19-validated)
// ---------------------------------------------------------------------------
__global__ __launch_bounds__(256) void k_fc3f(
    const float* __restrict__ P2,     // [4][256][256]
    const float* __restrict__ sf2, const float* __restrict__ cf2,
    const float* __restrict__ W,      // wf3 [800][256]
    const float* __restrict__ bias,
    float* __restrict__ f2out,        // [256][256] (d_out tail)
    float* __restrict__ C)            // [256][800]
{
    __shared__ float As[32][36];
    __shared__ float Ws[32][36];

    const int tid = threadIdx.x;
    const int bm = blockIdx.x * 32, bn = blockIdx.y * 32;
    const int ml = (tid >> 4) * 2, nl = (tid & 15) * 2;
    const int row = tid >> 3, kq = (tid & 7) * 4;

    float acc00 = 0.f, acc01 = 0.f, acc10 = 0.f, acc11 = 0.f;

    for (int k0 = 0; k0 < 256; k0 += 32) {
        const int ch = k0 + kq;
        const size_t ro = (size_t)(bm + row) * 256 + ch;
        const float4 p0 = *(const float4*)(P2 + ro);
        const float4 p1 = *(const float4*)(P2 + 65536 + ro);
        const float4 p2 = *(const float4*)(P2 + 131072 + ro);
        const float4 p3 = *(const float4*)(P2 + 196608 + ro);
        const float4 s4 = *(const float4*)(sf2 + ch);
        const float4 c4 = *(const float4*)(cf2 + ch);
        float4 av;
        av.x = fmaxf(fmaf(s4.x, p0.x + p1.x + p2.x + p3.x, c4.x), 0.f);
        av.y = fmaxf(fmaf(s4.y, p0.y + p1.y + p2.y + p3.y, c4.y), 0.f);
        av.z = fmaxf(fmaf(s4.z, p0.z + p1.z + p2.z + p3.z, c4.z), 0.f);
        av.w = fmaxf(fmaf(s4.w, p0.w + p1.w + p2.w + p3.w, c4.w), 0.f);
        if (blockIdx.y == 0)
            *(float4*)(f2out + ro) = av;          // materialize f2 (once)
        const float4 wv = *(const float4*)(W + (size_t)(bn + row) * 256 + ch);
        __syncthreads();
        *(float4*)(&As[row][kq]) = av;
        *(float4*)(&Ws[row][kq]) = wv;
        __syncthreads();
        const float4* a0p = (const float4*)(&As[ml][0]);
        const float4* a1p = (const float4*)(&As[ml + 1][0]);
        const float4* b0p = (const float4*)(&Ws[nl][0]);
        const float4* b1p = (const float4*)(&Ws[nl + 1][0]);
        #pragma unroll
        for (int q = 0; q < 8; ++q) {
            const float4 a0 = a0p[q], a1 = a1p[q], b0 = b0p[q], b1 = b1p[q];
            acc00 = fmaf(a0.x, b0.x, fmaf(a0.y, b0.y, fmaf(a0.z, b0.z, fmaf(a0.w, b0.w, acc00))));
            acc01 = fmaf(a0.x, b1.x, fmaf(a0.y, b1.y, fmaf(a0.z, b1.z, fmaf(a0.w, b1.w, acc01))));
            acc10 = fmaf(a1.x, b0.x, fmaf(a1.y, b0.y, fmaf(a1.z, b0.z, fmaf(a1.w, b0.w, acc10))));
            acc11 = fmaf(a1.x, b1.x, fmaf(a1.y, b1.y, fmaf(a1.z, b1.z, fmaf(a1.w, b1.w, acc11))));
        }
    }

    const int n0 = bn + nl, n1 = n0 + 1;
    float* cr0 = C + (size_t)(bm + ml) * 800 + n0;
    cr0[0] = acc00 + bias[n0]; cr0[1] = acc01 + bias[n1];
    float* cr1 = C + (size_t)(bm + ml + 1) * 800 + n0;
    cr1[0] = acc10 + bias[n0]; cr1[1] = acc11 + bias[n1];
}

// ---------------------------------------------------------------------------
extern "C" void kernel_launch(void* const* d_in, const int* in_sizes, int n_in,
                              void* d_out, int out_size, void* d_ws, size_t ws_size,
                              hipStream_t stream)
{
    const float* pts     = (const float*)d_in[0];
    const float* info    = (const float*)d_in[2];
    const float* w_info  = (const float*)d_in[3];
    const float* b_info  = (const float*)d_in[4];
    const float* g_info  = (const float*)d_in[5];
    const float* be_info = (const float*)d_in[6];
    const float* m_info  = (const float*)d_in[7];
    const float* v_info  = (const float*)d_in[8];
    const float* w2      = (const float*)d_in[9];
    const float* b2      = (const float*)d_in[10];
    const float* g2      = (const float*)d_in[11];
    const float* be2     = (const float*)d_in[12];
    const float* m2      = (const float*)d_in[13];
    const float* v2      = (const float*)d_in[14];
    const float* w3      = (const float*)d_in[15];
    const float* b3      = (const float*)d_in[16];
    const float* g3      = (const float*)d_in[17];
    const float* be3     = (const float*)d_in[18];
    const float* m3      = (const float*)d_in[19];
    const float* v3      = (const float*)d_in[20];
    const float* wf1     = (const float*)d_in[21];
    const float* bf1     = (const float*)d_in[22];
    const float* gf1     = (const float*)d_in[23];
    const float* bef1    = (const float*)d_in[24];
    const float* mf1     = (const float*)d_in[25];
    const float* vf1     = (const float*)d_in[26];
    const float* wf2     = (const float*)d_in[27];
    const float* bf2     = (const float*)d_in[28];
    const float* gf2     = (const float*)d_in[29];
    const float* bef2    = (const float*)d_in[30];
    const float* mf2     = (const float*)d_in[31];
    const float* vf2     = (const float*)d_in[32];
    const float* wf3     = (const float*)d_in[33];
    const float* bf3     = (const float*)d_in[34];

    float* ws = (float*)d_ws;
    // live ranges (launches serialize):
    //   gpart [0..491520)        edgehalf -> mid2
    //   h2h/h2l [491520..1015808) mid2 -> s3
    //   fp [0..524288)           fc1p -> fc2p   (overlaps gpart+h2h head: both dead)
    //   P2 [524288..786432)      fc2p -> fc3f   (overlaps h2h tail/h2l head: dead)
    float*          gpart = ws;                                  // [256][2][15][64]
    unsigned short* h2h   = (unsigned short*)(ws + 491520);      // 524288 bf16
    unsigned short* h2l   = (unsigned short*)(ws + 753664);      // 524288 bf16
    float*          g     = ws + 1015808;                        // 262144
    unsigned short* Bh    = (unsigned short*)(ws + 1277952);     // 131072 bf16
    unsigned short* Bl    = (unsigned short*)(ws + 1343488);     // 131072 bf16
    float*          bias3 = ws + 1409024;                        // 1024
    float4*         w2q   = (float4*)(ws + 1410048);             // 8192
    float*          bias2 = ws + 1418240;                        // 128
    float4*         qTab4 = (float4*)(ws + 1418624);             // 256
    float*          sf1   = ws + 1418880;                        // 512
    float*          cf1   = ws + 1419392;                        // 512
    float*          sf2   = ws + 1419904;                        // 256
    float*          cf2   = ws + 1420160;                        // 256
    unsigned short* Bedge = (unsigned short*)(ws + 1420416);     // 1024 bf16 used
    float*          fp    = ws;                                  // [4][256][512]
    float*          P2    = ws + 524288;                         // [4][256][256]

    float* ret = (float*)d_out;            // [256, 800]
    float* f2  = ret + 256 * 800;          // [256, 256]

    k_pre<<<66, 256, 0, stream>>>(
        w3, b3, g3, be3, m3, v3,
        w2, b2, g2, be2, m2, v2,
        w_info, b_info, g_info, be_info, m_info, v_info,
        bf1, gf1, bef1, mf1, vf1,
        bf2, gf2, bef2, mf2, vf2,
        Bh, Bl, bias3, w2q, bias2, Bedge, qTab4, sf1, cf1, sf2, cf2);

    k_edgehalf<<<512, 512, 0, stream>>>(info, Bedge, gpart);

    k_mid2<<<256, 256, 0, stream>>>(gpart, pts, qTab4, w2q, bias2, h2h, h2l);

    k_s3<<<256, 512, 0, stream>>>(h2h, h2l, Bh, Bl, bias3, g);

    k_fc1p<<<dim3(8, 16, 4), 256, 0, stream>>>(g, wf1, fp);

    k_fc2p<<<dim3(8, 8, 4), 256, 0, stream>>>(fp, sf1, cf1, wf2, P2);

    k_fc3f<<<dim3(8, 25), 256, 0, stream>>>(P2, sf2, cf2, wf3, bf3, f2, ret);
}

// Round 21
// 66.453 us; speedup vs baseline: 1.1573x; 1.1573x over previous
//
#include <hip/hip_runtime.h>
#include <math.h>

#define EPS 1e-5f

typedef __attribute__((ext_vector_type(8))) short short8v;
typedef __attribute__((ext_vector_type(4))) float f32x4;
typedef __attribute__((ext_vector_type(16))) float f32x16;

// ---- bf16 split helpers (RNE) ----
__device__ __forceinline__ unsigned short bf16r(float x) {
    unsigned u = __float_as_uint(x);
    return (unsigned short)((u + 0x7FFFu + ((u >> 16) & 1u)) >> 16);
}
__device__ __forceinline__ float bf2f(unsigned short h) {
    return __uint_as_float(((unsigned)h) << 16);
}
__device__ __forceinline__ unsigned packhl(float x) {
    const unsigned short h = bf16r(x);
    const unsigned short l = bf16r(x - bf2f(h));
    return (unsigned)h | ((unsigned)l << 16);
}

// ---------------------------------------------------------------------------
// k_pre (66 blocks): Bpack (conv3 bf16-split B), w2q/bias2, Bedge32, qTab4,
// bias3, sf1/cf1, sf2/cf2.  (R17/R19-validated)
// ---------------------------------------------------------------------------
__global__ __launch_bounds__(256) void k_pre(
    const float* __restrict__ w3, const float* __restrict__ b3,
    const float* __restrict__ g3, const float* __restrict__ be3,
    const float* __restrict__ m3, const float* __restrict__ v3,
    const float* __restrict__ w2, const float* __restrict__ b2,
    const float* __restrict__ g2, const float* __restrict__ be2,
    const float* __restrict__ m2, const float* __restrict__ v2,
    const float* __restrict__ w_info, const float* __restrict__ b_info,
    const float* __restrict__ g_info, const float* __restrict__ be_info,
    const float* __restrict__ m_info, const float* __restrict__ v_info,
    const float* __restrict__ bf1, const float* __restrict__ gf1,
    const float* __restrict__ bef1, const float* __restrict__ mf1,
    const float* __restrict__ vf1,
    const float* __restrict__ bf2, const float* __restrict__ gf2,
    const float* __restrict__ bef2, const float* __restrict__ mf2,
    const float* __restrict__ vf2,
    unsigned short* __restrict__ Bh, unsigned short* __restrict__ Bl,
    float* __restrict__ bias3,
    float4* __restrict__ w2q, float* __restrict__ bias2,
    unsigned short* __restrict__ Bedge,   // [2][64][8] bf16 (32x32 frags)
    float4* __restrict__ qTab4,
    float* __restrict__ sf1, float* __restrict__ cf1,
    float* __restrict__ sf2, float* __restrict__ cf2)
{
    const int blk = blockIdx.x, tid = threadIdx.x;
    if (blk < 64) {
        const int t = blk * 256 + tid;        // (kt,nt,lane)
        const int kt = t >> 12;
        const int nt = (t >> 6) & 63;
        const int lane = t & 63;
        const int o  = nt * 16 + (lane & 15);
        const int kb = kt * 32 + ((lane >> 4) << 3);
        const float a3 = g3[o] * rsqrtf(v3[o] + EPS);
        unsigned short hi[8], lo[8];
        #pragma unroll
        for (int j = 0; j < 8; ++j) {
            const float wv = a3 * w3[(size_t)o * 128 + kb + j];
            hi[j] = bf16r(wv);
            lo[j] = bf16r(wv - bf2f(hi[j]));
        }
        #pragma unroll
        for (int j = 0; j < 8; ++j) {
            Bh[(size_t)t * 8 + j] = hi[j];
            Bl[(size_t)t * 8 + j] = lo[j];
        }
    } else if (blk == 64) {
        for (int idx = tid; idx < 2048; idx += 256) {
            const int o2 = idx & 127, cq = idx >> 7;
            const float a2 = g2[o2] * rsqrtf(v2[o2] + EPS);
            const float4 w = *(const float4*)(w2 + (size_t)o2 * 64 + cq * 4);
            w2q[cq * 128 + o2] = make_float4(a2 * w.x, a2 * w.y, a2 * w.z, a2 * w.w);
        }
        if (tid < 128) {
            const float a2 = g2[tid] * rsqrtf(v2[tid] + EPS);
            bias2[tid] = a2 * (b2[tid] - m2[tid]) + be2[tid];
        }
    } else {
        if (tid < 128) {
            const int nt = tid >> 6, lane = tid & 63;
            const int grp = lane >> 5;
            const int o = nt * 32 + (lane & 31);
            const float a = g_info[o] * rsqrtf(v_info[o] + EPS);
            const float c0 = a * w_info[o*6+0];
            const float c1 = a * w_info[o*6+1];
            const float c2 = a * w_info[o*6+2];
            const unsigned short ch0 = bf16r(c0), ch1 = bf16r(c1), ch2 = bf16r(c2);
            const unsigned short cl0 = bf16r(c0 - bf2f(ch0));
            const unsigned short cl1 = bf16r(c1 - bf2f(ch1));
            const unsigned short cl2 = bf16r(c2 - bf2f(ch2));
            unsigned short out[8] = {0,0,0,0,0,0,0,0};
            if (grp == 0) {
                out[0]=ch0; out[1]=ch1; out[2]=ch2;
                out[3]=cl0; out[4]=cl1; out[5]=cl2;
                out[6]=ch0; out[7]=ch1;
            } else {
                out[0]=ch2;
            }
            #pragma unroll
            for (int j = 0; j < 8; ++j)
                Bedge[(size_t)(nt*64 + lane)*8 + j] = out[j];
        }
        if (tid < 64) {
            const int o = tid;
            const float w0 = w_info[o*6+0], w1 = w_info[o*6+1], w2c = w_info[o*6+2];
            const float w3c = w_info[o*6+3], w4 = w_info[o*6+4], w5 = w_info[o*6+5];
            const float a = g_info[o] * rsqrtf(v_info[o] + EPS);
            qTab4[o] = make_float4(a*(w3c-w0), a*(w4-w1), a*(w5-w2c),
                                   a*(b_info[o]-m_info[o]) + be_info[o]);
        }
        for (int c = tid; c < 1024; c += 256) {
            const float a3 = g3[c] * rsqrtf(v3[c] + EPS);
            bias3[c] = a3 * (b3[c] - m3[c]) + be3[c];
        }
        for (int c = tid; c < 512; c += 256) {
            const float s = gf1[c] * rsqrtf(vf1[c] + EPS);
            sf1[c] = s;
            cf1[c] = s * (bf1[c] - mf1[c]) + bef1[c];
        }
        {
            const int c = tid;
            const float s = gf2[c] * rsqrtf(vf2[c] + EPS);
            sf2[c] = s;
            cf2[c] = s * (bf2[c] - mf2[c]) + bef2[c];
        }
    }
}

// ---------------------------------------------------------------------------
// k_edgeS3: FULLY FUSED per-b pipeline: edge-conv (32x32x16 MFMA) + max(K)
// + bias + relu -> conv2 -> h2 (bf16 hi/lo, kept in LDS) -> conv3 (bf16x3
// MFMA) + global max over N -> g.
// R20 lesson: half-splitting edgemm regressed (not latency-bound); instead
// remove KNOWN overheads: 2 launches + the h2 global round-trip + s3's
// A-frag global reloads.  Edge phase = exact R19-validated loop (unroll 1,
// VGPR-safe); s3 phase = exact R19-validated loop with A-frags from LDS.
// LDS: 93600 + 3840 + 2*4096 = 105.4 KB (1 blk/CU, 8 waves - unchanged).
// ---------------------------------------------------------------------------
__global__ __launch_bounds__(512) void k_edgeS3(
    const float* __restrict__ pts,        // [256,15,3]
    const float* __restrict__ info,       // [256,520,15,3]
    const unsigned short* __restrict__ Bedge,  // [2][64][8]
    const float4* __restrict__ qTab4,     // [64]
    const float4* __restrict__ w2q,       // [16][128]
    const float* __restrict__ bias2,      // [128]
    const unsigned short* __restrict__ Bh,   // conv3 B hi [4][64][64][8]
    const unsigned short* __restrict__ Bl,   // conv3 B lo
    const float* __restrict__ bias3,      // [1024]
    float* __restrict__ gout)             // [256,1024]
{
    __shared__ unsigned dsb[23400];       // 93600 B  [k][n][c] packed hi|lo
    __shared__ float h1s[960];            // [15][64]
    __shared__ unsigned short h2hL[2048]; // [16][128] bf16 hi
    __shared__ unsigned short h2lL[2048]; // [16][128] bf16 lo

    const int tid = threadIdx.x;
    const int b = blockIdx.x;

    { // coalesced staging + bf16 hi/lo packing
        const float4* src = (const float4*)(info + (size_t)b * 23400);
        uint4* dst = (uint4*)dsb;
        for (int i = tid; i < 5850; i += 512) {
            const float4 v = src[i];
            uint4 pv;
            pv.x = packhl(v.x); pv.y = packhl(v.y);
            pv.z = packhl(v.z); pv.w = packhl(v.w);
            dst[i] = pv;
        }
    }
    __syncthreads();

    const int wave = tid >> 6, lane = tid & 63;
    const int la = lane & 31;
    const bool hiHalf = lane >= 32;

    {   // ---- edge-conv phase (R19-validated) ----
        short8v bfrag0 = *(const short8v*)(Bedge + (size_t)(0*64 + lane)*8);
        short8v bfrag1 = *(const short8v*)(Bedge + (size_t)(1*64 + lane)*8);

        const f32x16 zero16 = {0.f,0.f,0.f,0.f,0.f,0.f,0.f,0.f,
                               0.f,0.f,0.f,0.f,0.f,0.f,0.f,0.f};

        for (int n = wave; n < 15; n += 8) {
            float m0 = -INFINITY, m1 = -INFINITY;

            #pragma unroll 1
            for (int mt = 0; mt < 17; ++mt) {
                int row = mt*32 + la;
                row = row > 519 ? 519 : row;
                const unsigned* p = dsb + row*45 + n*3;
                int4 ai;
                if (!hiHalf) {
                    const unsigned w0 = p[0], w1 = p[1], w2 = p[2];
                    ai.x = (int)((w0 & 0xFFFFu) | (w1 << 16));        // dh0,dh1
                    ai.y = (int)((w2 & 0xFFFFu) | (w0 << 16));        // dh2,dh0
                    ai.z = (int)((w1 & 0xFFFFu) | (w2 << 16));        // dh1,dh2
                    ai.w = (int)((w0 >> 16) | (w1 & 0xFFFF0000u));    // dl0,dl1
                } else {
                    const unsigned w2 = p[2];
                    ai.x = (int)(w2 >> 16);                           // dl2
                    ai.y = 0; ai.z = 0; ai.w = 0;
                }
                const short8v afrag = *(short8v*)&ai;
                const f32x16 r0 = __builtin_amdgcn_mfma_f32_32x32x16_bf16(afrag, bfrag0, zero16, 0,0,0);
                const f32x16 r1 = __builtin_amdgcn_mfma_f32_32x32x16_bf16(afrag, bfrag1, zero16, 0,0,0);
                #pragma unroll
                for (int c = 0; c < 16; ++c) {
                    m0 = fmaxf(m0, r0[c]);
                    m1 = fmaxf(m1, r1[c]);
                }
            }
            m0 = fmaxf(m0, __shfl_xor(m0, 32));
            m1 = fmaxf(m1, __shfl_xor(m1, 32));

            if (lane < 32) {
                const float x0 = pts[b*45 + n*3 + 0];
                const float x1 = pts[b*45 + n*3 + 1];
                const float x2 = pts[b*45 + n*3 + 2];
                {
                    const int o = lane;
                    const float4 qv = qTab4[o];
                    const float bias = fmaf(qv.x, x0, fmaf(qv.y, x1, fmaf(qv.z, x2, qv.w)));
                    h1s[n*64 + o] = fmaxf(m0 + bias, 0.f);
                }
                {
                    const int o = 32 + lane;
                    const float4 qv = qTab4[o];
                    const float bias = fmaf(qv.x, x0, fmaf(qv.y, x1, fmaf(qv.z, x2, qv.w)));
                    h1s[n*64 + o] = fmaxf(m1 + bias, 0.f);
                }
            }
        }
    }
    __syncthreads();

    // ---- conv2 phase -> h2 in LDS (bf16 hi/lo; row 15 = pad 0) ----
    for (int idx = tid; idx < 2048; idx += 512) {
        const int o2 = idx & 127, n = idx >> 7;
        float val = 0.f;
        if (n < 15) {
            float acc = 0.f;
            #pragma unroll
            for (int cq = 0; cq < 16; ++cq) {
                const float4 h4 = *(const float4*)(&h1s[n*64 + cq*4]);
                const float4 w4 = w2q[cq*128 + o2];
                acc = fmaf(w4.x, h4.x, fmaf(w4.y, h4.y,
                      fmaf(w4.z, h4.z, fmaf(w4.w, h4.w, acc))));
            }
            val = fmaxf(acc + bias2[o2], 0.f);
        }
        const unsigned short hi = bf16r(val);
        const unsigned short lo = bf16r(val - bf2f(hi));
        h2hL[idx] = hi;
        h2lL[idx] = lo;
    }
    __syncthreads();

    // ---- conv3 + global-max phase (R19 k_s3, A-frags now from LDS) ----
    {
        const int arow = lane & 15, agrp = lane >> 4;

        short8v ahi[4], alo[4];
        {
            const unsigned short* Ab = h2hL + arow*128 + agrp*8;
            const unsigned short* Al = h2lL + arow*128 + agrp*8;
            #pragma unroll
            for (int kt = 0; kt < 4; ++kt) {
                ahi[kt] = *(const short8v*)(Ab + kt*32);
                alo[kt] = *(const short8v*)(Al + kt*32);
            }
        }

        for (int ntl = 0; ntl < 8; ++ntl) {
            const int nt = wave * 8 + ntl;
            f32x4 a0 = {0.f, 0.f, 0.f, 0.f};
            f32x4 a1 = a0, a2 = a0;
            #pragma unroll
            for (int kt = 0; kt < 4; ++kt) {
                const size_t off = (((size_t)kt*64 + nt)*64 + lane) * 8;
                const short8v bh = *(const short8v*)(Bh + off);
                const short8v bl = *(const short8v*)(Bl + off);
                a0 = __builtin_amdgcn_mfma_f32_16x16x32_bf16(ahi[kt], bh, a0, 0, 0, 0);
                a1 = __builtin_amdgcn_mfma_f32_16x16x32_bf16(ahi[kt], bl, a1, 0, 0, 0);
                a2 = __builtin_amdgcn_mfma_f32_16x16x32_bf16(alo[kt], bh, a2, 0, 0, 0);
            }
            const float r0 = a0[0] + a1[0] + a2[0];
            const float r1 = a0[1] + a1[1] + a2[1];
            const float r2 = a0[2] + a1[2] + a2[2];
            const float r3 = a0[3] + a1[3] + a2[3];
            float m = fmaxf(fmaxf(r0, r1), r2);
            if (agrp != 3) m = fmaxf(m, r3);          // exclude pad row 15
            m = fmaxf(m, __shfl_xor(m, 16));
            m = fmaxf(m, __shfl_xor(m, 32));
            if (lane < 16)
                gout[(size_t)b*1024 + nt*16 + lane] = m + bias3[nt*16 + lane];
        }
    }
}

// ---------------------------------------------------------------------------
// k_fc1p: fc1 split-K=4 raw partials.  grid (8,16,4).  (R19-validated)
// ---------------------------------------------------------------------------
__global__ __launch_bounds__(256) void k_fc1p(
    const float* __restrict__ A,      // g [256][1024]
    const float* __restrict__ W,      // wf1 [512][1024]
    float* __restrict__ P)            // [4][256][512]
{
    __shared__ float As[32][36];
    __shared__ float Ws[32][36];

    const int tid = threadIdx.x;
    const int bm = blockIdx.x * 32, bn = blockIdx.y * 32;
    const int ks = blockIdx.z;
    const int ml = (tid >> 4) * 2, nl = (tid & 15) * 2;
    const int row = tid >> 3, kq = (tid & 7) * 4;

    float acc00 = 0.f, acc01 = 0.f, acc10 = 0.f, acc11 = 0.f;

    for (int k0 = 0; k0 < 256; k0 += 32) {
        const int ch = ks * 256 + k0 + kq;
        const float4 av = *(const float4*)(A + (size_t)(bm + row) * 1024 + ch);
        const float4 wv = *(const float4*)(W + (size_t)(bn + row) * 1024 + ch);
        __syncthreads();
        *(float4*)(&As[row][kq]) = av;
        *(float4*)(&Ws[row][kq]) = wv;
        __syncthreads();
        const float4* a0p = (const float4*)(&As[ml][0]);
        const float4* a1p = (const float4*)(&As[ml + 1][0]);
        const float4* b0p = (const float4*)(&Ws[nl][0]);
        const float4* b1p = (const float4*)(&Ws[nl + 1][0]);
        #pragma unroll
        for (int q = 0; q < 8; ++q) {
            const float4 a0 = a0p[q], a1 = a1p[q], b0 = b0p[q], b1 = b1p[q];
            acc00 = fmaf(a0.x, b0.x, fmaf(a0.y, b0.y, fmaf(a0.z, b0.z, fmaf(a0.w, b0.w, acc00))));
            acc01 = fmaf(a0.x, b1.x, fmaf(a0.y, b1.y, fmaf(a0.z, b1.z, fmaf(a0.w, b1.w, acc01))));
            acc10 = fmaf(a1.x, b0.x, fmaf(a1.y, b0.y, fmaf(a1.z, b0.z, fmaf(a1.w, b0.w, acc10))));
            acc11 = fmaf(a1.x, b1.x, fmaf(a1.y, b1.y, fmaf(a1.z, b1.z, fmaf(a1.w, b1.w, acc11))));
        }
    }
    float* p0 = P + (size_t)ks * 131072 + (size_t)(bm + ml) * 512 + bn + nl;
    p0[0] = acc00; p0[1] = acc01;
    float* p1 = p0 + 512;
    p1[0] = acc10; p1[1] = acc11;
}

// ---------------------------------------------------------------------------
// k_fc2p: fc2 split-K=4.  A-tile finishes f1 from 4 fp partials.  (R19)
// ---------------------------------------------------------------------------
__global__ __launch_bounds__(256) void k_fc2p(
    const float* __restrict__ fp,     // [4][256][512]
    const float* __restrict__ sf1, const float* __restrict__ cf1,
    const float* __restrict__ W,      // wf2 [256][512]
    float* __restrict__ P2)           // [4][256][256]
{
    __shared__ float As[32][36];
    __shared__ float Ws[32][36];

    const int tid = threadIdx.x;
    const int bm = blockIdx.x * 32, bn = blockIdx.y * 32;
    const int ks = blockIdx.z;
    const int ml = (tid >> 4) * 2, nl = (tid & 15) * 2;
    const int row = tid >> 3, kq = (tid & 7) * 4;

    float acc00 = 0.f, acc01 = 0.f, acc10 = 0.f, acc11 = 0.f;

    for (int k0 = 0; k0 < 128; k0 += 32) {
        const int ch = ks * 128 + k0 + kq;
        const size_t ro = (size_t)(bm + row) * 512 + ch;
        const float4 p0 = *(const float4*)(fp + ro);
        const float4 p1 = *(const float4*)(fp + 131072 + ro);
        const float4 p2 = *(const float4*)(fp + 262144 + ro);
        const float4 p3 = *(const float4*)(fp + 393216 + ro);
        const float4 s4 = *(const float4*)(sf1 + ch);
        const float4 c4 = *(const float4*)(cf1 + ch);
        float4 av;
        av.x = fmaxf(fmaf(s4.x, p0.x + p1.x + p2.x + p3.x, c4.x), 0.f);
        av.y = fmaxf(fmaf(s4.y, p0.y + p1.y + p2.y + p3.y, c4.y), 0.f);
        av.z = fmaxf(fmaf(s4.z, p0.z + p1.z + p2.z + p3.z, c4.z), 0.f);
        av.w = fmaxf(fmaf(s4.w, p0.w + p1.w + p2.w + p3.w, c4.w), 0.f);
        const float4 wv = *(const float4*)(W + (size_t)(bn + row) * 512 + ch);
        __syncthreads();
        *(float4*)(&As[row][kq]) = av;
        *(float4*)(&Ws[row][kq]) = wv;
        __syncthreads();
        const float4* a0p = (const float4*)(&As[ml][0]);
        const float4* a1p = (const float4*)(&As[ml + 1][0]);
        const float4* b0p = (const float4*)(&Ws[nl][0]);
        const float4* b1p = (const float4*)(&Ws[nl + 1][0]);
        #pragma unroll
        for (int q = 0; q < 8; ++q) {
            const float4 a0 = a0p[q], a1 = a1p[q], b0 = b0p[q], b1 = b1p[q];
            acc00 = fmaf(a0.x, b0.x, fmaf(a0.y, b0.y, fmaf(a0.z, b0.z, fmaf(a0.w, b0.w, acc00))));
            acc01 = fmaf(a0.x, b1.x, fmaf(a0.y, b1.y, fmaf(a0.z, b1.z, fmaf(a0.w, b1.w, acc01))));
            acc10 = fmaf(a1.x, b0.x, fmaf(a1.y, b0.y, fmaf(a1.z, b0.z, fmaf(a1.w, b0.w, acc10))));
            acc11 = fmaf(a1.x, b1.x, fmaf(a1.y, b1.y, fmaf(a1.z, b1.z, fmaf(a1.w, b1.w, acc11))));
        }
    }
    float* q0 = P2 + (size_t)ks * 65536 + (size_t)(bm + ml) * 256 + bn + nl;
    q0[0] = acc00; q0[1] = acc01;
    float* q1 = q0 + 256;
    q1[0] = acc10; q1[1] = acc11;
}

// ---------------------------------------------------------------------------
// k_fc3f: fc3 with fused f2 epilogue.  (R19-validated)
// ---------------------------------------------------------------------------
__global__ __launch_bounds__(256) void k_fc3f(
    const float* __restrict__ P2,     // [4][256][256]
    const float* __restrict__ sf2, const float* __restrict__ cf2,
    const float* __restrict__ W,      // wf3 [800][256]
    const float* __restrict__ bias,
    float* __restrict__ f2out,        // [256][256] (d_out tail)
    float* __restrict__ C)            // [256][800]
{
    __shared__ float As[32][36];
    __shared__ float Ws[32][36];

    const int tid = threadIdx.x;
    const int bm = blockIdx.x * 32, bn = blockIdx.y * 32;
    const int ml = (tid >> 4) * 2, nl = (tid & 15) * 2;
    const int row = tid >> 3, kq = (tid & 7) * 4;

    float acc00 = 0.f, acc01 = 0.f, acc10 = 0.f, acc11 = 0.f;

    for (int k0 = 0; k0 < 256; k0 += 32) {
        const int ch = k0 + kq;
        const size_t ro = (size_t)(bm + row) * 256 + ch;
        const float4 p0 = *(const float4*)(P2 + ro);
        const float4 p1 = *(const float4*)(P2 + 65536 + ro);
        const float4 p2 = *(const float4*)(P2 + 131072 + ro);
        const float4 p3 = *(const float4*)(P2 + 196608 + ro);
        const float4 s4 = *(const float4*)(sf2 + ch);
        const float4 c4 = *(const float4*)(cf2 + ch);
        float4 av;
        av.x = fmaxf(fmaf(s4.x, p0.x + p1.x + p2.x + p3.x, c4.x), 0.f);
        av.y = fmaxf(fmaf(s4.y, p0.y + p1.y + p2.y + p3.y, c4.y), 0.f);
        av.z = fmaxf(fmaf(s4.z, p0.z + p1.z + p2.z + p3.z, c4.z), 0.f);
        av.w = fmaxf(fmaf(s4.w, p0.w + p1.w + p2.w + p3.w, c4.w), 0.f);
        if (blockIdx.y == 0)
            *(float4*)(f2out + ro) = av;          // materialize f2 (once)
        const float4 wv = *(const float4*)(W + (size_t)(bn + row) * 256 + ch);
        __syncthreads();
        *(float4*)(&As[row][kq]) = av;
        *(float4*)(&Ws[row][kq]) = wv;
        __syncthreads();
        const float4* a0p = (const float4*)(&As[ml][0]);
        const float4* a1p = (const float4*)(&As[ml + 1][0]);
        const float4* b0p = (const float4*)(&Ws[nl][0]);
        const float4* b1p = (const float4*)(&Ws[nl + 1][0]);
        #pragma unroll
        for (int q = 0; q < 8; ++q) {
            const float4 a0 = a0p[q], a1 = a1p[q], b0 = b0p[q], b1 = b1p[q];
            acc00 = fmaf(a0.x, b0.x, fmaf(a0.y, b0.y, fmaf(a0.z, b0.z, fmaf(a0.w, b0.w, acc00))));
            acc01 = fmaf(a0.x, b1.x, fmaf(a0.y, b1.y, fmaf(a0.z, b1.z, fmaf(a0.w, b1.w, acc01))));
            acc10 = fmaf(a1.x, b0.x, fmaf(a1.y, b0.y, fmaf(a1.z, b0.z, fmaf(a1.w, b0.w, acc10))));
            acc11 = fmaf(a1.x, b1.x, fmaf(a1.y, b1.y, fmaf(a1.z, b1.z, fmaf(a1.w, b1.w, acc11))));
        }
    }

    const int n0 = bn + nl, n1 = n0 + 1;
    float* cr0 = C + (size_t)(bm + ml) * 800 + n0;
    cr0[0] = acc00 + bias[n0]; cr0[1] = acc01 + bias[n1];
    float* cr1 = C + (size_t)(bm + ml + 1) * 800 + n0;
    cr1[0] = acc10 + bias[n0]; cr1[1] = acc11 + bias[n1];
}

// ---------------------------------------------------------------------------
extern "C" void kernel_launch(void* const* d_in, const int* in_sizes, int n_in,
                              void* d_out, int out_size, void* d_ws, size_t ws_size,
                              hipStream_t stream)
{
    const float* pts     = (const float*)d_in[0];
    const float* info    = (const float*)d_in[2];
    const float* w_info  = (const float*)d_in[3];
    const float* b_info  = (const float*)d_in[4];
    const float* g_info  = (const float*)d_in[5];
    const float* be_info = (const float*)d_in[6];
    const float* m_info  = (const float*)d_in[7];
    const float* v_info  = (const float*)d_in[8];
    const float* w2      = (const float*)d_in[9];
    const float* b2      = (const float*)d_in[10];
    const float* g2      = (const float*)d_in[11];
    const float* be2     = (const float*)d_in[12];
    const float* m2      = (const float*)d_in[13];
    const float* v2      = (const float*)d_in[14];
    const float* w3      = (const float*)d_in[15];
    const float* b3      = (const float*)d_in[16];
    const float* g3      = (const float*)d_in[17];
    const float* be3     = (const float*)d_in[18];
    const float* m3      = (const float*)d_in[19];
    const float* v3      = (const float*)d_in[20];
    const float* wf1     = (const float*)d_in[21];
    const float* bf1     = (const float*)d_in[22];
    const float* gf1     = (const float*)d_in[23];
    const float* bef1    = (const float*)d_in[24];
    const float* mf1     = (const float*)d_in[25];
    const float* vf1     = (const float*)d_in[26];
    const float* wf2     = (const float*)d_in[27];
    const float* bf2     = (const float*)d_in[28];
    const float* gf2     = (const float*)d_in[29];
    const float* bef2    = (const float*)d_in[30];
    const float* mf2     = (const float*)d_in[31];
    const float* vf2     = (const float*)d_in[32];
    const float* wf3     = (const float*)d_in[33];
    const float* bf3     = (const float*)d_in[34];

    float* ws = (float*)d_ws;
    // live ranges (launches serialize):
    //   g [1015808..1277952)   edgeS3 -> fc1p
    //   fp [0..524288)         fc1p -> fc2p
    //   P2 [524288..786432)    fc2p -> fc3f
    float*          g     = ws + 1015808;                        // 262144
    unsigned short* Bh    = (unsigned short*)(ws + 1277952);     // 131072 bf16
    unsigned short* Bl    = (unsigned short*)(ws + 1343488);     // 131072 bf16
    float*          bias3 = ws + 1409024;                        // 1024
    float4*         w2q   = (float4*)(ws + 1410048);             // 8192
    float*          bias2 = ws + 1418240;                        // 128
    float4*         qTab4 = (float4*)(ws + 1418624);             // 256
    float*          sf1   = ws + 1418880;                        // 512
    float*          cf1   = ws + 1419392;                        // 512
    float*          sf2   = ws + 1419904;                        // 256
    float*          cf2   = ws + 1420160;                        // 256
    unsigned short* Bedge = (unsigned short*)(ws + 1420416);     // 1024 bf16 used
    float*          fp    = ws;                                  // [4][256][512]
    float*          P2    = ws + 524288;                         // [4][256][256]

    float* ret = (float*)d_out;            // [256, 800]
    float* f2  = ret + 256 * 800;          // [256, 256]

    k_pre<<<66, 256, 0, stream>>>(
        w3, b3, g3, be3, m3, v3,
        w2, b2, g2, be2, m2, v2,
        w_info, b_info, g_info, be_info, m_info, v_info,
        bf1, gf1, bef1, mf1, vf1,
        bf2, gf2, bef2, mf2, vf2,
        Bh, Bl, bias3, w2q, bias2, Bedge, qTab4, sf1, cf1, sf2, cf2);

    k_edgeS3<<<256, 512, 0, stream>>>(pts, info, Bedge, qTab4,
                                      w2q, bias2, Bh, Bl, bias3, g);

    k_fc1p<<<dim3(8, 16, 4), 256, 0, stream>>>(g, wf1, fp);

    k_fc2p<<<dim3(8, 8, 4), 256, 0, stream>>>(fp, sf1, cf1, wf2, P2);

    k_fc3f<<<dim3(8, 25), 256, 0, stream>>>(P2, sf2, cf2, wf3, bf3, f2, ret);
}

// Round 23
// 62.023 us; speedup vs baseline: 1.2400x; 1.0714x over previous
//
#include <hip/hip_runtime.h>
#include <math.h>

#define EPS 1e-5f

typedef __attribute__((ext_vector_type(8))) short short8v;
typedef __attribute__((ext_vector_type(4))) float f32x4;
typedef __attribute__((ext_vector_type(16))) float f32x16;

// ---- bf16 split helpers (RNE) ----
__device__ __forceinline__ unsigned short bf16r(float x) {
    unsigned u = __float_as_uint(x);
    return (unsigned short)((u + 0x7FFFu + ((u >> 16) & 1u)) >> 16);
}
__device__ __forceinline__ float bf2f(unsigned short h) {
    return __uint_as_float(((unsigned)h) << 16);
}
__device__ __forceinline__ unsigned packhl(float x) {
    const unsigned short h = bf16r(x);
    const unsigned short l = bf16r(x - bf2f(h));
    return (unsigned)h | ((unsigned)l << 16);
}

// ---------------------------------------------------------------------------
// k_pre (386 blocks): conv3 Bpack (0..63), w2q/bias2 (64), Bedge/qTab/bias3/
// sf/cf (65), wf1 pack -> B1 (66..321), wf2 pack -> B2 (322..385).
// B-frag layout (32x32x16, validated): value = W[n=nt*32+(lane&31)]
// [kt*16+(lane>>5)*8+j] stored at ((kt*NT+nt)*64+lane)*8+j.
// ---------------------------------------------------------------------------
__global__ __launch_bounds__(256) void k_pre(
    const float* __restrict__ w3, const float* __restrict__ b3,
    const float* __restrict__ g3, const float* __restrict__ be3,
    const float* __restrict__ m3, const float* __restrict__ v3,
    const float* __restrict__ w2, const float* __restrict__ b2,
    const float* __restrict__ g2, const float* __restrict__ be2,
    const float* __restrict__ m2, const float* __restrict__ v2,
    const float* __restrict__ w_info, const float* __restrict__ b_info,
    const float* __restrict__ g_info, const float* __restrict__ be_info,
    const float* __restrict__ m_info, const float* __restrict__ v_info,
    const float* __restrict__ bf1, const float* __restrict__ gf1,
    const float* __restrict__ bef1, const float* __restrict__ mf1,
    const float* __restrict__ vf1,
    const float* __restrict__ bf2, const float* __restrict__ gf2,
    const float* __restrict__ bef2, const float* __restrict__ mf2,
    const float* __restrict__ vf2,
    const float* __restrict__ wf1, const float* __restrict__ wf2,
    unsigned short* __restrict__ Bh, unsigned short* __restrict__ Bl,
    float* __restrict__ bias3,
    float4* __restrict__ w2q, float* __restrict__ bias2,
    unsigned short* __restrict__ Bedge,
    float4* __restrict__ qTab4,
    float* __restrict__ sf1, float* __restrict__ cf1,
    float* __restrict__ sf2, float* __restrict__ cf2,
    unsigned short* __restrict__ B1h, unsigned short* __restrict__ B1l,
    unsigned short* __restrict__ B2h, unsigned short* __restrict__ B2l)
{
    const int blk = blockIdx.x, tid = threadIdx.x;
    if (blk < 64) {
        const int t = blk * 256 + tid;        // (kt,nt,lane) for conv3 B
        const int kt = t >> 12;
        const int nt = (t >> 6) & 63;
        const int lane = t & 63;
        const int o  = nt * 16 + (lane & 15);
        const int kb = kt * 32 + ((lane >> 4) << 3);
        const float a3 = g3[o] * rsqrtf(v3[o] + EPS);
        #pragma unroll
        for (int j = 0; j < 8; ++j) {
            const float wv = a3 * w3[(size_t)o * 128 + kb + j];
            const unsigned short hi = bf16r(wv);
            Bh[(size_t)t * 8 + j] = hi;
            Bl[(size_t)t * 8 + j] = bf16r(wv - bf2f(hi));
        }
    } else if (blk == 64) {
        for (int idx = tid; idx < 2048; idx += 256) {
            const int o2 = idx & 127, cq = idx >> 7;
            const float a2 = g2[o2] * rsqrtf(v2[o2] + EPS);
            const float4 w = *(const float4*)(w2 + (size_t)o2 * 64 + cq * 4);
            w2q[cq * 128 + o2] = make_float4(a2 * w.x, a2 * w.y, a2 * w.z, a2 * w.w);
        }
        if (tid < 128) {
            const float a2 = g2[tid] * rsqrtf(v2[tid] + EPS);
            bias2[tid] = a2 * (b2[tid] - m2[tid]) + be2[tid];
        }
    } else if (blk == 65) {
        if (tid < 128) {
            const int nt = tid >> 6, lane = tid & 63;
            const int grp = lane >> 5;
            const int o = nt * 32 + (lane & 31);
            const float a = g_info[o] * rsqrtf(v_info[o] + EPS);
            const float c0 = a * w_info[o*6+0];
            const float c1 = a * w_info[o*6+1];
            const float c2 = a * w_info[o*6+2];
            const unsigned short ch0 = bf16r(c0), ch1 = bf16r(c1), ch2 = bf16r(c2);
            const unsigned short cl0 = bf16r(c0 - bf2f(ch0));
            const unsigned short cl1 = bf16r(c1 - bf2f(ch1));
            const unsigned short cl2 = bf16r(c2 - bf2f(ch2));
            unsigned short out[8] = {0,0,0,0,0,0,0,0};
            if (grp == 0) {
                out[0]=ch0; out[1]=ch1; out[2]=ch2;
                out[3]=cl0; out[4]=cl1; out[5]=cl2;
                out[6]=ch0; out[7]=ch1;
            } else {
                out[0]=ch2;
            }
            #pragma unroll
            for (int j = 0; j < 8; ++j)
                Bedge[(size_t)(nt*64 + lane)*8 + j] = out[j];
        }
        if (tid < 64) {
            const int o = tid;
            const float w0 = w_info[o*6+0], w1 = w_info[o*6+1], w2c = w_info[o*6+2];
            const float w3c = w_info[o*6+3], w4 = w_info[o*6+4], w5 = w_info[o*6+5];
            const float a = g_info[o] * rsqrtf(v_info[o] + EPS);
            qTab4[o] = make_float4(a*(w3c-w0), a*(w4-w1), a*(w5-w2c),
                                   a*(b_info[o]-m_info[o]) + be_info[o]);
        }
        for (int c = tid; c < 1024; c += 256) {
            const float a3 = g3[c] * rsqrtf(v3[c] + EPS);
            bias3[c] = a3 * (b3[c] - m3[c]) + be3[c];
        }
        for (int c = tid; c < 512; c += 256) {
            const float s = gf1[c] * rsqrtf(vf1[c] + EPS);
            sf1[c] = s;
            cf1[c] = s * (bf1[c] - mf1[c]) + bef1[c];
        }
        {
            const int c = tid;
            const float s = gf2[c] * rsqrtf(vf2[c] + EPS);
            sf2[c] = s;
            cf2[c] = s * (bf2[c] - mf2[c]) + bef2[c];
        }
    } else if (blk < 322) {
        // wf1 pack: idx = kt*1024 + nt*64 + lane, kt<64, nt<16
        const int idx = (blk - 66) * 256 + tid;
        const int lane = idx & 63;
        const int nt = (idx >> 6) & 15;
        const int kt = idx >> 10;
        const int n  = nt * 32 + (lane & 31);
        const int kb = kt * 16 + ((lane >> 5) << 3);
        #pragma unroll
        for (int j = 0; j < 8; ++j) {
            const float wv = wf1[(size_t)n * 1024 + kb + j];
            const unsigned short hi = bf16r(wv);
            B1h[(size_t)idx * 8 + j] = hi;
            B1l[(size_t)idx * 8 + j] = bf16r(wv - bf2f(hi));
        }
    } else {
        // wf2 pack: idx = kt*512 + nt*64 + lane, kt<32, nt<8
        const int idx = (blk - 322) * 256 + tid;
        const int lane = idx & 63;
        const int nt = (idx >> 6) & 7;
        const int kt = idx >> 9;
        const int n  = nt * 32 + (lane & 31);
        const int kb = kt * 16 + ((lane >> 5) << 3);
        #pragma unroll
        for (int j = 0; j < 8; ++j) {
            const float wv = wf2[(size_t)n * 512 + kb + j];
            const unsigned short hi = bf16r(wv);
            B2h[(size_t)idx * 8 + j] = hi;
            B2l[(size_t)idx * 8 + j] = bf16r(wv - bf2f(hi));
        }
    }
}

// ---------------------------------------------------------------------------
// k_edgeS3: fused edge-conv + max + conv2 + conv3 + global max.  (R21-
// validated; g emitted as bf16 hi/lo for the MFMA fc1.)
// ---------------------------------------------------------------------------
__global__ __launch_bounds__(512) void k_edgeS3(
    const float* __restrict__ pts,
    const float* __restrict__ info,
    const unsigned short* __restrict__ Bedge,
    const float4* __restrict__ qTab4,
    const float4* __restrict__ w2q,
    const float* __restrict__ bias2,
    const unsigned short* __restrict__ Bh,
    const unsigned short* __restrict__ Bl,
    const float* __restrict__ bias3,
    unsigned short* __restrict__ ghi,     // [256][1024] bf16 hi
    unsigned short* __restrict__ glo)     // [256][1024] bf16 lo
{
    __shared__ unsigned dsb[23400];
    __shared__ float h1s[960];
    __shared__ unsigned short h2hL[2048];
    __shared__ unsigned short h2lL[2048];

    const int tid = threadIdx.x;
    const int b = blockIdx.x;

    {
        const float4* src = (const float4*)(info + (size_t)b * 23400);
        uint4* dst = (uint4*)dsb;
        for (int i = tid; i < 5850; i += 512) {
            const float4 v = src[i];
            uint4 pv;
            pv.x = packhl(v.x); pv.y = packhl(v.y);
            pv.z = packhl(v.z); pv.w = packhl(v.w);
            dst[i] = pv;
        }
    }
    __syncthreads();

    const int wave = tid >> 6, lane = tid & 63;
    const int la = lane & 31;
    const bool hiHalf = lane >= 32;

    {   // ---- edge-conv phase ----
        short8v bfrag0 = *(const short8v*)(Bedge + (size_t)(0*64 + lane)*8);
        short8v bfrag1 = *(const short8v*)(Bedge + (size_t)(1*64 + lane)*8);

        const f32x16 zero16 = {0.f,0.f,0.f,0.f,0.f,0.f,0.f,0.f,
                               0.f,0.f,0.f,0.f,0.f,0.f,0.f,0.f};

        for (int n = wave; n < 15; n += 8) {
            float m0 = -INFINITY, m1 = -INFINITY;

            #pragma unroll 1
            for (int mt = 0; mt < 17; ++mt) {
                int row = mt*32 + la;
                row = row > 519 ? 519 : row;
                const unsigned* p = dsb + row*45 + n*3;
                int4 ai;
                if (!hiHalf) {
                    const unsigned w0 = p[0], w1 = p[1], w2 = p[2];
                    ai.x = (int)((w0 & 0xFFFFu) | (w1 << 16));
                    ai.y = (int)((w2 & 0xFFFFu) | (w0 << 16));
                    ai.z = (int)((w1 & 0xFFFFu) | (w2 << 16));
                    ai.w = (int)((w0 >> 16) | (w1 & 0xFFFF0000u));
                } else {
                    const unsigned w2 = p[2];
                    ai.x = (int)(w2 >> 16);
                    ai.y = 0; ai.z = 0; ai.w = 0;
                }
                const short8v afrag = *(short8v*)&ai;
                const f32x16 r0 = __builtin_amdgcn_mfma_f32_32x32x16_bf16(afrag, bfrag0, zero16, 0,0,0);
                const f32x16 r1 = __builtin_amdgcn_mfma_f32_32x32x16_bf16(afrag, bfrag1, zero16, 0,0,0);
                #pragma unroll
                for (int c = 0; c < 16; ++c) {
                    m0 = fmaxf(m0, r0[c]);
                    m1 = fmaxf(m1, r1[c]);
                }
            }
            m0 = fmaxf(m0, __shfl_xor(m0, 32));
            m1 = fmaxf(m1, __shfl_xor(m1, 32));

            if (lane < 32) {
                const float x0 = pts[b*45 + n*3 + 0];
                const float x1 = pts[b*45 + n*3 + 1];
                const float x2 = pts[b*45 + n*3 + 2];
                {
                    const int o = lane;
                    const float4 qv = qTab4[o];
                    const float bias = fmaf(qv.x, x0, fmaf(qv.y, x1, fmaf(qv.z, x2, qv.w)));
                    h1s[n*64 + o] = fmaxf(m0 + bias, 0.f);
                }
                {
                    const int o = 32 + lane;
                    const float4 qv = qTab4[o];
                    const float bias = fmaf(qv.x, x0, fmaf(qv.y, x1, fmaf(qv.z, x2, qv.w)));
                    h1s[n*64 + o] = fmaxf(m1 + bias, 0.f);
                }
            }
        }
    }
    __syncthreads();

    // ---- conv2 phase -> h2 in LDS ----
    for (int idx = tid; idx < 2048; idx += 512) {
        const int o2 = idx & 127, n = idx >> 7;
        float val = 0.f;
        if (n < 15) {
            float acc = 0.f;
            #pragma unroll
            for (int cq = 0; cq < 16; ++cq) {
                const float4 h4 = *(const float4*)(&h1s[n*64 + cq*4]);
                const float4 w4 = w2q[cq*128 + o2];
                acc = fmaf(w4.x, h4.x, fmaf(w4.y, h4.y,
                      fmaf(w4.z, h4.z, fmaf(w4.w, h4.w, acc))));
            }
            val = fmaxf(acc + bias2[o2], 0.f);
        }
        const unsigned short hi = bf16r(val);
        const unsigned short lo = bf16r(val - bf2f(hi));
        h2hL[idx] = hi;
        h2lL[idx] = lo;
    }
    __syncthreads();

    // ---- conv3 + global-max phase -> g bf16 hi/lo ----
    {
        const int arow = lane & 15, agrp = lane >> 4;

        short8v ahi[4], alo[4];
        {
            const unsigned short* Ab = h2hL + arow*128 + agrp*8;
            const unsigned short* Al = h2lL + arow*128 + agrp*8;
            #pragma unroll
            for (int kt = 0; kt < 4; ++kt) {
                ahi[kt] = *(const short8v*)(Ab + kt*32);
                alo[kt] = *(const short8v*)(Al + kt*32);
            }
        }

        for (int ntl = 0; ntl < 8; ++ntl) {
            const int nt = wave * 8 + ntl;
            f32x4 a0 = {0.f, 0.f, 0.f, 0.f};
            f32x4 a1 = a0, a2 = a0;
            #pragma unroll
            for (int kt = 0; kt < 4; ++kt) {
                const size_t off = (((size_t)kt*64 + nt)*64 + lane) * 8;
                const short8v bh = *(const short8v*)(Bh + off);
                const short8v bl = *(const short8v*)(Bl + off);
                a0 = __builtin_amdgcn_mfma_f32_16x16x32_bf16(ahi[kt], bh, a0, 0, 0, 0);
                a1 = __builtin_amdgcn_mfma_f32_16x16x32_bf16(ahi[kt], bl, a1, 0, 0, 0);
                a2 = __builtin_amdgcn_mfma_f32_16x16x32_bf16(alo[kt], bh, a2, 0, 0, 0);
            }
            const float r0 = a0[0] + a1[0] + a2[0];
            const float r1 = a0[1] + a1[1] + a2[1];
            const float r2 = a0[2] + a1[2] + a2[2];
            const float r3 = a0[3] + a1[3] + a2[3];
            float m = fmaxf(fmaxf(r0, r1), r2);
            if (agrp != 3) m = fmaxf(m, r3);
            m = fmaxf(m, __shfl_xor(m, 16));
            m = fmaxf(m, __shfl_xor(m, 32));
            if (lane < 16) {
                const float val = m + bias3[nt*16 + lane];
                const unsigned short hi = bf16r(val);
                ghi[(size_t)b*1024 + nt*16 + lane] = hi;
                glo[(size_t)b*1024 + nt*16 + lane] = bf16r(val - bf2f(hi));
            }
        }
    }
}

// ---------------------------------------------------------------------------
// k_fc1m: fc1 via bf16x3 MFMA.  grid (8,16); 4 waves split K=1024 (16 kt
// each), chained-C 3xMFMA per kt; LDS cross-wave reduce; epilogue
// relu(sf1*sum+cf1) -> f1 bf16 hi/lo.
// ---------------------------------------------------------------------------
__global__ __launch_bounds__(256) void k_fc1m(
    const unsigned short* __restrict__ gh,   // [256][1024]
    const unsigned short* __restrict__ gl,
    const unsigned short* __restrict__ B1h,  // [64][16][64][8]
    const unsigned short* __restrict__ B1l,
    const float* __restrict__ sf1, const float* __restrict__ cf1,
    unsigned short* __restrict__ f1h,        // [256][512]
    unsigned short* __restrict__ f1l)
{
    __shared__ float part[4][32][33];

    const int tid = threadIdx.x;
    const int bm = blockIdx.x * 32, bn = blockIdx.y * 32;
    const int wave = tid >> 6, lane = tid & 63;
    const int m = bm + (lane & 31);
    const int kgrp = (lane >> 5) << 3;

    f32x16 acc = {0.f,0.f,0.f,0.f,0.f,0.f,0.f,0.f,
                  0.f,0.f,0.f,0.f,0.f,0.f,0.f,0.f};

    for (int kt = wave*16; kt < wave*16 + 16; ++kt) {
        const int kb = kt*16 + kgrp;
        const short8v ah = *(const short8v*)(gh + (size_t)m*1024 + kb);
        const short8v al = *(const short8v*)(gl + (size_t)m*1024 + kb);
        const size_t boff = ((size_t)kt*1024 + blockIdx.y*64 + lane) * 8;
        const short8v bh = *(const short8v*)(B1h + boff);
        const short8v bl = *(const short8v*)(B1l + boff);
        acc = __builtin_amdgcn_mfma_f32_32x32x16_bf16(ah, bh, acc, 0,0,0);
        acc = __builtin_amdgcn_mfma_f32_32x32x16_bf16(ah, bl, acc, 0,0,0);
        acc = __builtin_amdgcn_mfma_f32_32x32x16_bf16(al, bh, acc, 0,0,0);
    }
    {
        const int n = lane & 31, mhl = (lane >> 5) << 2;
        #pragma unroll
        for (int reg = 0; reg < 16; ++reg) {
            const int mrow = (reg & 3) + 8*(reg >> 2) + mhl;
            part[wave][mrow][n] = acc[reg];
        }
    }
    __syncthreads();

    for (int i = tid; i < 1024; i += 256) {
        const int lm = i >> 5, ln = i & 31;
        const float sum = part[0][lm][ln] + part[1][lm][ln]
                        + part[2][lm][ln] + part[3][lm][ln];
        const int ch = bn + ln;
        const float val = fmaxf(fmaf(sf1[ch], sum, cf1[ch]), 0.f);
        const unsigned short hi = bf16r(val);
        f1h[(size_t)(bm + lm)*512 + ch] = hi;
        f1l[(size_t)(bm + lm)*512 + ch] = bf16r(val - bf2f(hi));
    }
}

// ---------------------------------------------------------------------------
// k_fc2m: fc2 via bf16x3 MFMA.  grid (8,8); 4 waves split K=512 (8 kt each);
// epilogue relu(sf2*sum+cf2) -> f2 fp32 (d_out tail; fc3 reads it).
// ---------------------------------------------------------------------------
__global__ __launch_bounds__(256) void k_fc2m(
    const unsigned short* __restrict__ f1h,  // [256][512]
    const unsigned short* __restrict__ f1l,
    const unsigned short* __restrict__ B2h,  // [32][8][64][8]
    const unsigned short* __restrict__ B2l,
    const float* __restrict__ sf2, const float* __restrict__ cf2,
    float* __restrict__ f2out)               // [256][256]
{
    __shared__ float part[4][32][33];

    const int tid = threadIdx.x;
    const int bm = blockIdx.x * 32, bn = blockIdx.y * 32;
    const int wave = tid >> 6, lane = tid & 63;
    const int m = bm + (lane & 31);
    const int kgrp = (lane >> 5) << 3;

    f32x16 acc = {0.f,0.f,0.f,0.f,0.f,0.f,0.f,0.f,
                  0.f,0.f,0.f,0.f,0.f,0.f,0.f,0.f};

    for (int kt = wave*8; kt < wave*8 + 8; ++kt) {
        const int kb = kt*16 + kgrp;
        const short8v ah = *(const short8v*)(f1h + (size_t)m*512 + kb);
        const short8v al = *(const short8v*)(f1l + (size_t)m*512 + kb);
        const size_t boff = ((size_t)kt*512 + blockIdx.y*64 + lane) * 8;
        const short8v bh = *(const short8v*)(B2h + boff);
        const short8v bl = *(const short8v*)(B2l + boff);
        acc = __builtin_amdgcn_mfma_f32_32x32x16_bf16(ah, bh, acc, 0,0,0);
        acc = __builtin_amdgcn_mfma_f32_32x32x16_bf16(ah, bl, acc, 0,0,0);
        acc = __builtin_amdgcn_mfma_f32_32x32x16_bf16(al, bh, acc, 0,0,0);
    }
    {
        const int n = lane & 31, mhl = (lane >> 5) << 2;
        #pragma unroll
        for (int reg = 0; reg < 16; ++reg) {
            const int mrow = (reg & 3) + 8*(reg >> 2) + mhl;
            part[wave][mrow][n] = acc[reg];
        }
    }
    __syncthreads();

    for (int i = tid; i < 1024; i += 256) {
        const int lm = i >> 5, ln = i & 31;
        const float sum = part[0][lm][ln] + part[1][lm][ln]
                        + part[2][lm][ln] + part[3][lm][ln];
        const int ch = bn + ln;
        f2out[(size_t)(bm + lm)*256 + ch] =
            fmaxf(fmaf(sf2[ch], sum, cf2[ch]), 0.f);
    }
}

// ---------------------------------------------------------------------------
// k_fc3: plain fp32 GEMM (final layer; R8-validated).  C = A*W^T + bias.
// ---------------------------------------------------------------------------
__global__ __launch_bounds__(256) void k_fc3(
    const float* __restrict__ A, const float* __restrict__ W,
    const float* __restrict__ bias, float* __restrict__ C, int K, int Nc)
{
    __shared__ float As[32][36];
    __shared__ float Ws[32][36];

    const int tid = threadIdx.x;
    const int bm = blockIdx.x * 32, bn = blockIdx.y * 32;
    const int ml = (tid >> 4) * 2, nl = (tid & 15) * 2;
    const int row = tid >> 3, kq = (tid & 7) * 4;

    float acc00 = 0.f, acc01 = 0.f, acc10 = 0.f, acc11 = 0.f;

    for (int k0 = 0; k0 < K; k0 += 32) {
        const float4 av = *(const float4*)(A + (size_t)(bm + row) * K + k0 + kq);
        const float4 wv = *(const float4*)(W + (size_t)(bn + row) * K + k0 + kq);
        __syncthreads();
        *(float4*)(&As[row][kq]) = av;
        *(float4*)(&Ws[row][kq]) = wv;
        __syncthreads();
        const float4* a0p = (const float4*)(&As[ml][0]);
        const float4* a1p = (const float4*)(&As[ml + 1][0]);
        const float4* b0p = (const float4*)(&Ws[nl][0]);
        const float4* b1p = (const float4*)(&Ws[nl + 1][0]);
        #pragma unroll
        for (int q = 0; q < 8; ++q) {
            const float4 a0 = a0p[q], a1 = a1p[q], b0 = b0p[q], b1 = b1p[q];
            acc00 = fmaf(a0.x, b0.x, fmaf(a0.y, b0.y, fmaf(a0.z, b0.z, fmaf(a0.w, b0.w, acc00))));
            acc01 = fmaf(a0.x, b1.x, fmaf(a0.y, b1.y, fmaf(a0.z, b1.z, fmaf(a0.w, b1.w, acc01))));
            acc10 = fmaf(a1.x, b0.x, fmaf(a1.y, b0.y, fmaf(a1.z, b0.z, fmaf(a1.w, b0.w, acc10))));
            acc11 = fmaf(a1.x, b1.x, fmaf(a1.y, b1.y, fmaf(a1.z, b1.z, fmaf(a1.w, b1.w, acc11))));
        }
    }

    const int n0 = bn + nl, n1 = n0 + 1;
    float* cr0 = C + (size_t)(bm + ml) * Nc + n0;
    cr0[0] = acc00 + bias[n0]; cr0[1] = acc01 + bias[n1];
    float* cr1 = C + (size_t)(bm + ml + 1) * Nc + n0;
    cr1[0] = acc10 + bias[n0]; cr1[1] = acc11 + bias[n1];
}

// ---------------------------------------------------------------------------
extern "C" void kernel_launch(void* const* d_in, const int* in_sizes, int n_in,
                              void* d_out, int out_size, void* d_ws, size_t ws_size,
                              hipStream_t stream)
{
    const float* pts     = (const float*)d_in[0];
    const float* info    = (const float*)d_in[2];
    const float* w_info  = (const float*)d_in[3];
    const float* b_info  = (const float*)d_in[4];
    const float* g_info  = (const float*)d_in[5];
    const float* be_info = (const float*)d_in[6];
    const float* m_info  = (const float*)d_in[7];
    const float* v_info  = (const float*)d_in[8];
    const float* w2      = (const float*)d_in[9];
    const float* b2      = (const float*)d_in[10];
    const float* g2      = (const float*)d_in[11];
    const float* be2     = (const float*)d_in[12];
    const float* m2      = (const float*)d_in[13];
    const float* v2      = (const float*)d_in[14];
    const float* w3      = (const float*)d_in[15];
    const float* b3      = (const float*)d_in[16];
    const float* g3      = (const float*)d_in[17];
    const float* be3     = (const float*)d_in[18];
    const float* m3      = (const float*)d_in[19];
    const float* v3      = (const float*)d_in[20];
    const float* wf1     = (const float*)d_in[21];
    const float* bf1     = (const float*)d_in[22];
    const float* gf1     = (const float*)d_in[23];
    const float* bef1    = (const float*)d_in[24];
    const float* mf1     = (const float*)d_in[25];
    const float* vf1     = (const float*)d_in[26];
    const float* wf2     = (const float*)d_in[27];
    const float* bf2     = (const float*)d_in[28];
    const float* gf2     = (const float*)d_in[29];
    const float* bef2    = (const float*)d_in[30];
    const float* mf2     = (const float*)d_in[31];
    const float* vf2     = (const float*)d_in[32];
    const float* wf3     = (const float*)d_in[33];
    const float* bf3     = (const float*)d_in[34];

    float* ws = (float*)d_ws;
    // fc-MFMA region -- R22 BUG FIX: sizes in FLOAT-SLOTS = shorts/2.
    //   ghi [0..131072)           256*1024 shorts
    //   glo [131072..262144)
    //   f1h [262144..327680)      256*512 shorts
    //   f1l [327680..393216)
    //   B1h [393216..655360)      512*1024 shorts
    //   B1l [655360..917504)
    //   B2h [917504..983040)      256*512 shorts
    //   B2l [983040..1048576)     -> ends below constants at 1277952.  OK.
    unsigned short* ghi   = (unsigned short*)(ws + 0);
    unsigned short* glo   = (unsigned short*)(ws + 131072);
    unsigned short* f1h   = (unsigned short*)(ws + 262144);
    unsigned short* f1l   = (unsigned short*)(ws + 327680);
    unsigned short* B1h   = (unsigned short*)(ws + 393216);
    unsigned short* B1l   = (unsigned short*)(ws + 655360);
    unsigned short* B2h   = (unsigned short*)(ws + 917504);
    unsigned short* B2l   = (unsigned short*)(ws + 983040);
    // constants region (unchanged offsets):
    unsigned short* Bh    = (unsigned short*)(ws + 1277952);     // 262144 shorts
    unsigned short* Bl    = (unsigned short*)(ws + 1343488);     // 262144 shorts
    float*          bias3 = ws + 1409024;                        // 1024
    float4*         w2q   = (float4*)(ws + 1410048);             // 8192
    float*          bias2 = ws + 1418240;                        // 128
    float4*         qTab4 = (float4*)(ws + 1418624);             // 256
    float*          sf1   = ws + 1418880;                        // 512
    float*          cf1   = ws + 1419392;                        // 512
    float*          sf2   = ws + 1419904;                        // 256
    float*          cf2   = ws + 1420160;                        // 256
    unsigned short* Bedge = (unsigned short*)(ws + 1420416);     // 1024 bf16 used

    float* ret = (float*)d_out;            // [256, 800]
    float* f2  = ret + 256 * 800;          // [256, 256]

    k_pre<<<386, 256, 0, stream>>>(
        w3, b3, g3, be3, m3, v3,
        w2, b2, g2, be2, m2, v2,
        w_info, b_info, g_info, be_info, m_info, v_info,
        bf1, gf1, bef1, mf1, vf1,
        bf2, gf2, bef2, mf2, vf2,
        wf1, wf2,
        Bh, Bl, bias3, w2q, bias2, Bedge, qTab4, sf1, cf1, sf2, cf2,
        B1h, B1l, B2h, B2l);

    k_edgeS3<<<256, 512, 0, stream>>>(pts, info, Bedge, qTab4,
                                      w2q, bias2, Bh, Bl, bias3, ghi, glo);

    k_fc1m<<<dim3(8, 16), 256, 0, stream>>>(ghi, glo, B1h, B1l,
                                            sf1, cf1, f1h, f1l);

    k_fc2m<<<dim3(8, 8), 256, 0, stream>>>(f1h, f1l, B2h, B2l,
                                           sf2, cf2, f2);

    k_fc3<<<dim3(8, 25), 256, 0, stream>>>(f2, wf3, bf3, ret, 256, 800);
}

// Round 24
// 60.160 us; speedup vs baseline: 1.2784x; 1.0310x over previous
//
#include <hip/hip_runtime.h>
#include <math.h>

#define EPS 1e-5f

typedef __attribute__((ext_vector_type(8))) short short8v;
typedef __attribute__((ext_vector_type(4))) float f32x4;
typedef __attribute__((ext_vector_type(16))) float f32x16;

// ---- bf16 split helpers (RNE) ----
__device__ __forceinline__ unsigned short bf16r(float x) {
    unsigned u = __float_as_uint(x);
    return (unsigned short)((u + 0x7FFFu + ((u >> 16) & 1u)) >> 16);
}
__device__ __forceinline__ float bf2f(unsigned short h) {
    return __uint_as_float(((unsigned)h) << 16);
}
__device__ __forceinline__ unsigned packhl(float x) {
    const unsigned short h = bf16r(x);
    const unsigned short l = bf16r(x - bf2f(h));
    return (unsigned)h | ((unsigned)l << 16);
}

// ---------------------------------------------------------------------------
// k_pre (486 blocks): conv3 Bpack (0..63), w2q/bias2 (64), Bedge/qTab/bias3/
// sf/cf (65), wf1->B1 (66..321), wf2->B2 (322..385), wf3->B3 (386..485).
// B-frag layout (32x32x16, validated): value = W[n=nt*32+(lane&31)]
// [kt*16+(lane>>5)*8+j] stored at ((kt*NT+nt)*64+lane)*8+j.
// ---------------------------------------------------------------------------
__global__ __launch_bounds__(256) void k_pre(
    const float* __restrict__ w3, const float* __restrict__ b3,
    const float* __restrict__ g3, const float* __restrict__ be3,
    const float* __restrict__ m3, const float* __restrict__ v3,
    const float* __restrict__ w2, const float* __restrict__ b2,
    const float* __restrict__ g2, const float* __restrict__ be2,
    const float* __restrict__ m2, const float* __restrict__ v2,
    const float* __restrict__ w_info, const float* __restrict__ b_info,
    const float* __restrict__ g_info, const float* __restrict__ be_info,
    const float* __restrict__ m_info, const float* __restrict__ v_info,
    const float* __restrict__ bf1, const float* __restrict__ gf1,
    const float* __restrict__ bef1, const float* __restrict__ mf1,
    const float* __restrict__ vf1,
    const float* __restrict__ bf2, const float* __restrict__ gf2,
    const float* __restrict__ bef2, const float* __restrict__ mf2,
    const float* __restrict__ vf2,
    const float* __restrict__ wf1, const float* __restrict__ wf2,
    const float* __restrict__ wf3,
    unsigned short* __restrict__ Bh, unsigned short* __restrict__ Bl,
    float* __restrict__ bias3,
    float4* __restrict__ w2q, float* __restrict__ bias2,
    unsigned short* __restrict__ Bedge,
    float4* __restrict__ qTab4,
    float* __restrict__ sf1, float* __restrict__ cf1,
    float* __restrict__ sf2, float* __restrict__ cf2,
    unsigned short* __restrict__ B1h, unsigned short* __restrict__ B1l,
    unsigned short* __restrict__ B2h, unsigned short* __restrict__ B2l,
    unsigned short* __restrict__ B3h, unsigned short* __restrict__ B3l)
{
    const int blk = blockIdx.x, tid = threadIdx.x;
    if (blk < 64) {
        const int t = blk * 256 + tid;        // (kt,nt,lane) for conv3 B
        const int kt = t >> 12;
        const int nt = (t >> 6) & 63;
        const int lane = t & 63;
        const int o  = nt * 16 + (lane & 15);
        const int kb = kt * 32 + ((lane >> 4) << 3);
        const float a3 = g3[o] * rsqrtf(v3[o] + EPS);
        #pragma unroll
        for (int j = 0; j < 8; ++j) {
            const float wv = a3 * w3[(size_t)o * 128 + kb + j];
            const unsigned short hi = bf16r(wv);
            Bh[(size_t)t * 8 + j] = hi;
            Bl[(size_t)t * 8 + j] = bf16r(wv - bf2f(hi));
        }
    } else if (blk == 64) {
        for (int idx = tid; idx < 2048; idx += 256) {
            const int o2 = idx & 127, cq = idx >> 7;
            const float a2 = g2[o2] * rsqrtf(v2[o2] + EPS);
            const float4 w = *(const float4*)(w2 + (size_t)o2 * 64 + cq * 4);
            w2q[cq * 128 + o2] = make_float4(a2 * w.x, a2 * w.y, a2 * w.z, a2 * w.w);
        }
        if (tid < 128) {
            const float a2 = g2[tid] * rsqrtf(v2[tid] + EPS);
            bias2[tid] = a2 * (b2[tid] - m2[tid]) + be2[tid];
        }
    } else if (blk == 65) {
        if (tid < 128) {
            const int nt = tid >> 6, lane = tid & 63;
            const int grp = lane >> 5;
            const int o = nt * 32 + (lane & 31);
            const float a = g_info[o] * rsqrtf(v_info[o] + EPS);
            const float c0 = a * w_info[o*6+0];
            const float c1 = a * w_info[o*6+1];
            const float c2 = a * w_info[o*6+2];
            const unsigned short ch0 = bf16r(c0), ch1 = bf16r(c1), ch2 = bf16r(c2);
            const unsigned short cl0 = bf16r(c0 - bf2f(ch0));
            const unsigned short cl1 = bf16r(c1 - bf2f(ch1));
            const unsigned short cl2 = bf16r(c2 - bf2f(ch2));
            unsigned short out[8] = {0,0,0,0,0,0,0,0};
            if (grp == 0) {
                out[0]=ch0; out[1]=ch1; out[2]=ch2;
                out[3]=cl0; out[4]=cl1; out[5]=cl2;
                out[6]=ch0; out[7]=ch1;
            } else {
                out[0]=ch2;
            }
            #pragma unroll
            for (int j = 0; j < 8; ++j)
                Bedge[(size_t)(nt*64 + lane)*8 + j] = out[j];
        }
        if (tid < 64) {
            const int o = tid;
            const float w0 = w_info[o*6+0], w1 = w_info[o*6+1], w2c = w_info[o*6+2];
            const float w3c = w_info[o*6+3], w4 = w_info[o*6+4], w5 = w_info[o*6+5];
            const float a = g_info[o] * rsqrtf(v_info[o] + EPS);
            qTab4[o] = make_float4(a*(w3c-w0), a*(w4-w1), a*(w5-w2c),
                                   a*(b_info[o]-m_info[o]) + be_info[o]);
        }
        for (int c = tid; c < 1024; c += 256) {
            const float a3 = g3[c] * rsqrtf(v3[c] + EPS);
            bias3[c] = a3 * (b3[c] - m3[c]) + be3[c];
        }
        for (int c = tid; c < 512; c += 256) {
            const float s = gf1[c] * rsqrtf(vf1[c] + EPS);
            sf1[c] = s;
            cf1[c] = s * (bf1[c] - mf1[c]) + bef1[c];
        }
        {
            const int c = tid;
            const float s = gf2[c] * rsqrtf(vf2[c] + EPS);
            sf2[c] = s;
            cf2[c] = s * (bf2[c] - mf2[c]) + bef2[c];
        }
    } else if (blk < 322) {
        // wf1 pack: idx = kt*1024 + nt*64 + lane, kt<64, nt<16
        const int idx = (blk - 66) * 256 + tid;
        const int lane = idx & 63;
        const int nt = (idx >> 6) & 15;
        const int kt = idx >> 10;
        const int n  = nt * 32 + (lane & 31);
        const int kb = kt * 16 + ((lane >> 5) << 3);
        #pragma unroll
        for (int j = 0; j < 8; ++j) {
            const float wv = wf1[(size_t)n * 1024 + kb + j];
            const unsigned short hi = bf16r(wv);
            B1h[(size_t)idx * 8 + j] = hi;
            B1l[(size_t)idx * 8 + j] = bf16r(wv - bf2f(hi));
        }
    } else if (blk < 386) {
        // wf2 pack: idx = kt*512 + nt*64 + lane, kt<32, nt<8
        const int idx = (blk - 322) * 256 + tid;
        const int lane = idx & 63;
        const int nt = (idx >> 6) & 7;
        const int kt = idx >> 9;
        const int n  = nt * 32 + (lane & 31);
        const int kb = kt * 16 + ((lane >> 5) << 3);
        #pragma unroll
        for (int j = 0; j < 8; ++j) {
            const float wv = wf2[(size_t)n * 512 + kb + j];
            const unsigned short hi = bf16r(wv);
            B2h[(size_t)idx * 8 + j] = hi;
            B2l[(size_t)idx * 8 + j] = bf16r(wv - bf2f(hi));
        }
    } else {
        // wf3 pack: idx = kt*1600 + nt*64 + lane, kt<16, nt<25
        const int idx = (blk - 386) * 256 + tid;       // < 25600
        const int lane = idx & 63;
        const int g6 = idx >> 6;
        const int nt = g6 % 25;
        const int kt = g6 / 25;
        const int n  = nt * 32 + (lane & 31);          // < 800
        const int kb = kt * 16 + ((lane >> 5) << 3);
        #pragma unroll
        for (int j = 0; j < 8; ++j) {
            const float wv = wf3[(size_t)n * 256 + kb + j];
            const unsigned short hi = bf16r(wv);
            B3h[(size_t)idx * 8 + j] = hi;
            B3l[(size_t)idx * 8 + j] = bf16r(wv - bf2f(hi));
        }
    }
}

// ---------------------------------------------------------------------------
// k_edgeS3: fused edge-conv + max + conv2 + conv3 + global max (R23-valid.).
// New: depth-2 software pipeline on the edge-phase LDS reads (+3 VGPRs,
// NO extra f32x16 state - rule #10) + tree-shaped fmax (chain 16 -> 8).
// ---------------------------------------------------------------------------
__global__ __launch_bounds__(512) void k_edgeS3(
    const float* __restrict__ pts,
    const float* __restrict__ info,
    const unsigned short* __restrict__ Bedge,
    const float4* __restrict__ qTab4,
    const float4* __restrict__ w2q,
    const float* __restrict__ bias2,
    const unsigned short* __restrict__ Bh,
    const unsigned short* __restrict__ Bl,
    const float* __restrict__ bias3,
    unsigned short* __restrict__ ghi,     // [256][1024] bf16 hi
    unsigned short* __restrict__ glo)     // [256][1024] bf16 lo
{
    __shared__ unsigned dsb[23400];
    __shared__ float h1s[960];
    __shared__ unsigned short h2hL[2048];
    __shared__ unsigned short h2lL[2048];

    const int tid = threadIdx.x;
    const int b = blockIdx.x;

    {
        const float4* src = (const float4*)(info + (size_t)b * 23400);
        uint4* dst = (uint4*)dsb;
        for (int i = tid; i < 5850; i += 512) {
            const float4 v = src[i];
            uint4 pv;
            pv.x = packhl(v.x); pv.y = packhl(v.y);
            pv.z = packhl(v.z); pv.w = packhl(v.w);
            dst[i] = pv;
        }
    }
    __syncthreads();

    const int wave = tid >> 6, lane = tid & 63;
    const int la = lane & 31;
    const bool hiHalf = lane >= 32;

    {   // ---- edge-conv phase (depth-2 LDS prefetch) ----
        short8v bfrag0 = *(const short8v*)(Bedge + (size_t)(0*64 + lane)*8);
        short8v bfrag1 = *(const short8v*)(Bedge + (size_t)(1*64 + lane)*8);

        const f32x16 zero16 = {0.f,0.f,0.f,0.f,0.f,0.f,0.f,0.f,
                               0.f,0.f,0.f,0.f,0.f,0.f,0.f,0.f};

        for (int n = wave; n < 15; n += 8) {
            float m0 = -INFINITY, m1 = -INFINITY;
            const unsigned* pb = dsb + n*3;

            unsigned w0 = 0, w1 = 0, w2 = 0;
            {   // prologue: mt = 0 (row = la <= 31, no clamp needed)
                const unsigned* p = pb + la*45;
                if (!hiHalf) { w0 = p[0]; w1 = p[1]; }
                w2 = p[2];
            }

            #pragma unroll 1
            for (int mt = 0; mt < 17; ++mt) {
                unsigned nw0 = 0, nw1 = 0, nw2 = 0;
                if (mt < 16) {      // prefetch next row (hides under MFMA)
                    int nrow = (mt+1)*32 + la;
                    nrow = nrow > 519 ? 519 : nrow;
                    const unsigned* p = pb + nrow*45;
                    if (!hiHalf) { nw0 = p[0]; nw1 = p[1]; }
                    nw2 = p[2];
                }
                int4 ai;
                if (!hiHalf) {
                    ai.x = (int)((w0 & 0xFFFFu) | (w1 << 16));
                    ai.y = (int)((w2 & 0xFFFFu) | (w0 << 16));
                    ai.z = (int)((w1 & 0xFFFFu) | (w2 << 16));
                    ai.w = (int)((w0 >> 16) | (w1 & 0xFFFF0000u));
                } else {
                    ai.x = (int)(w2 >> 16);
                    ai.y = 0; ai.z = 0; ai.w = 0;
                }
                const short8v afrag = *(short8v*)&ai;
                const f32x16 r0 = __builtin_amdgcn_mfma_f32_32x32x16_bf16(afrag, bfrag0, zero16, 0,0,0);
                const f32x16 r1 = __builtin_amdgcn_mfma_f32_32x32x16_bf16(afrag, bfrag1, zero16, 0,0,0);
                #pragma unroll
                for (int c = 0; c < 16; c += 4) {
                    m0 = fmaxf(m0, fmaxf(fmaxf(r0[c], r0[c+1]),
                                         fmaxf(r0[c+2], r0[c+3])));
                    m1 = fmaxf(m1, fmaxf(fmaxf(r1[c], r1[c+1]),
                                         fmaxf(r1[c+2], r1[c+3])));
                }
                w0 = nw0; w1 = nw1; w2 = nw2;
            }
            m0 = fmaxf(m0, __shfl_xor(m0, 32));
            m1 = fmaxf(m1, __shfl_xor(m1, 32));

            if (lane < 32) {
                const float x0 = pts[b*45 + n*3 + 0];
                const float x1 = pts[b*45 + n*3 + 1];
                const float x2 = pts[b*45 + n*3 + 2];
                {
                    const int o = lane;
                    const float4 qv = qTab4[o];
                    const float bias = fmaf(qv.x, x0, fmaf(qv.y, x1, fmaf(qv.z, x2, qv.w)));
                    h1s[n*64 + o] = fmaxf(m0 + bias, 0.f);
                }
                {
                    const int o = 32 + lane;
                    const float4 qv = qTab4[o];
                    const float bias = fmaf(qv.x, x0, fmaf(qv.y, x1, fmaf(qv.z, x2, qv.w)));
                    h1s[n*64 + o] = fmaxf(m1 + bias, 0.f);
                }
            }
        }
    }
    __syncthreads();

    // ---- conv2 phase -> h2 in LDS ----
    for (int idx = tid; idx < 2048; idx += 512) {
        const int o2 = idx & 127, n = idx >> 7;
        float val = 0.f;
        if (n < 15) {
            float acc = 0.f;
            #pragma unroll
            for (int cq = 0; cq < 16; ++cq) {
                const float4 h4 = *(const float4*)(&h1s[n*64 + cq*4]);
                const float4 w4 = w2q[cq*128 + o2];
                acc = fmaf(w4.x, h4.x, fmaf(w4.y, h4.y,
                      fmaf(w4.z, h4.z, fmaf(w4.w, h4.w, acc))));
            }
            val = fmaxf(acc + bias2[o2], 0.f);
        }
        const unsigned short hi = bf16r(val);
        const unsigned short lo = bf16r(val - bf2f(hi));
        h2hL[idx] = hi;
        h2lL[idx] = lo;
    }
    __syncthreads();

    // ---- conv3 + global-max phase -> g bf16 hi/lo ----
    {
        const int arow = lane & 15, agrp = lane >> 4;

        short8v ahi[4], alo[4];
        {
            const unsigned short* Ab = h2hL + arow*128 + agrp*8;
            const unsigned short* Al = h2lL + arow*128 + agrp*8;
            #pragma unroll
            for (int kt = 0; kt < 4; ++kt) {
                ahi[kt] = *(const short8v*)(Ab + kt*32);
                alo[kt] = *(const short8v*)(Al + kt*32);
            }
        }

        for (int ntl = 0; ntl < 8; ++ntl) {
            const int nt = wave * 8 + ntl;
            f32x4 a0 = {0.f, 0.f, 0.f, 0.f};
            f32x4 a1 = a0, a2 = a0;
            #pragma unroll
            for (int kt = 0; kt < 4; ++kt) {
                const size_t off = (((size_t)kt*64 + nt)*64 + lane) * 8;
                const short8v bh = *(const short8v*)(Bh + off);
                const short8v bl = *(const short8v*)(Bl + off);
                a0 = __builtin_amdgcn_mfma_f32_16x16x32_bf16(ahi[kt], bh, a0, 0, 0, 0);
                a1 = __builtin_amdgcn_mfma_f32_16x16x32_bf16(ahi[kt], bl, a1, 0, 0, 0);
                a2 = __builtin_amdgcn_mfma_f32_16x16x32_bf16(alo[kt], bh, a2, 0, 0, 0);
            }
            const float r0 = a0[0] + a1[0] + a2[0];
            const float r1 = a0[1] + a1[1] + a2[1];
            const float r2 = a0[2] + a1[2] + a2[2];
            const float r3 = a0[3] + a1[3] + a2[3];
            float m = fmaxf(fmaxf(r0, r1), r2);
            if (agrp != 3) m = fmaxf(m, r3);
            m = fmaxf(m, __shfl_xor(m, 16));
            m = fmaxf(m, __shfl_xor(m, 32));
            if (lane < 16) {
                const float val = m + bias3[nt*16 + lane];
                const unsigned short hi = bf16r(val);
                ghi[(size_t)b*1024 + nt*16 + lane] = hi;
                glo[(size_t)b*1024 + nt*16 + lane] = bf16r(val - bf2f(hi));
            }
        }
    }
}

// ---------------------------------------------------------------------------
// k_fc1m: fc1 via bf16x3 MFMA.  (R23-validated)
// ---------------------------------------------------------------------------
__global__ __launch_bounds__(256) void k_fc1m(
    const unsigned short* __restrict__ gh,   // [256][1024]
    const unsigned short* __restrict__ gl,
    const unsigned short* __restrict__ B1h,  // [64][16][64][8]
    const unsigned short* __restrict__ B1l,
    const float* __restrict__ sf1, const float* __restrict__ cf1,
    unsigned short* __restrict__ f1h,        // [256][512]
    unsigned short* __restrict__ f1l)
{
    __shared__ float part[4][32][33];

    const int tid = threadIdx.x;
    const int bm = blockIdx.x * 32, bn = blockIdx.y * 32;
    const int wave = tid >> 6, lane = tid & 63;
    const int m = bm + (lane & 31);
    const int kgrp = (lane >> 5) << 3;

    f32x16 acc = {0.f,0.f,0.f,0.f,0.f,0.f,0.f,0.f,
                  0.f,0.f,0.f,0.f,0.f,0.f,0.f,0.f};

    for (int kt = wave*16; kt < wave*16 + 16; ++kt) {
        const int kb = kt*16 + kgrp;
        const short8v ah = *(const short8v*)(gh + (size_t)m*1024 + kb);
        const short8v al = *(const short8v*)(gl + (size_t)m*1024 + kb);
        const size_t boff = ((size_t)kt*1024 + blockIdx.y*64 + lane) * 8;
        const short8v bh = *(const short8v*)(B1h + boff);
        const short8v bl = *(const short8v*)(B1l + boff);
        acc = __builtin_amdgcn_mfma_f32_32x32x16_bf16(ah, bh, acc, 0,0,0);
        acc = __builtin_amdgcn_mfma_f32_32x32x16_bf16(ah, bl, acc, 0,0,0);
        acc = __builtin_amdgcn_mfma_f32_32x32x16_bf16(al, bh, acc, 0,0,0);
    }
    {
        const int n = lane & 31, mhl = (lane >> 5) << 2;
        #pragma unroll
        for (int reg = 0; reg < 16; ++reg) {
            const int mrow = (reg & 3) + 8*(reg >> 2) + mhl;
            part[wave][mrow][n] = acc[reg];
        }
    }
    __syncthreads();

    for (int i = tid; i < 1024; i += 256) {
        const int lm = i >> 5, ln = i & 31;
        const float sum = part[0][lm][ln] + part[1][lm][ln]
                        + part[2][lm][ln] + part[3][lm][ln];
        const int ch = bn + ln;
        const float val = fmaxf(fmaf(sf1[ch], sum, cf1[ch]), 0.f);
        const unsigned short hi = bf16r(val);
        f1h[(size_t)(bm + lm)*512 + ch] = hi;
        f1l[(size_t)(bm + lm)*512 + ch] = bf16r(val - bf2f(hi));
    }
}

// ---------------------------------------------------------------------------
// k_fc2m: fc2 via bf16x3 MFMA.  (R23-validated; new: also emits f2 as bf16
// hi/lo into workspace for the MFMA fc3.)
// ---------------------------------------------------------------------------
__global__ __launch_bounds__(256) void k_fc2m(
    const unsigned short* __restrict__ f1h,  // [256][512]
    const unsigned short* __restrict__ f1l,
    const unsigned short* __restrict__ B2h,  // [32][8][64][8]
    const unsigned short* __restrict__ B2l,
    const float* __restrict__ sf2, const float* __restrict__ cf2,
    float* __restrict__ f2out,               // [256][256] fp32 (d_out tail)
    unsigned short* __restrict__ f2h,        // [256][256] bf16 hi
    unsigned short* __restrict__ f2l)        // [256][256] bf16 lo
{
    __shared__ float part[4][32][33];

    const int tid = threadIdx.x;
    const int bm = blockIdx.x * 32, bn = blockIdx.y * 32;
    const int wave = tid >> 6, lane = tid & 63;
    const int m = bm + (lane & 31);
    const int kgrp = (lane >> 5) << 3;

    f32x16 acc = {0.f,0.f,0.f,0.f,0.f,0.f,0.f,0.f,
                  0.f,0.f,0.f,0.f,0.f,0.f,0.f,0.f};

    for (int kt = wave*8; kt < wave*8 + 8; ++kt) {
        const int kb = kt*16 + kgrp;
        const short8v ah = *(const short8v*)(f1h + (size_t)m*512 + kb);
        const short8v al = *(const short8v*)(f1l + (size_t)m*512 + kb);
        const size_t boff = ((size_t)kt*512 + blockIdx.y*64 + lane) * 8;
        const short8v bh = *(const short8v*)(B2h + boff);
        const short8v bl = *(const short8v*)(B2l + boff);
        acc = __builtin_amdgcn_mfma_f32_32x32x16_bf16(ah, bh, acc, 0,0,0);
        acc = __builtin_amdgcn_mfma_f32_32x32x16_bf16(ah, bl, acc, 0,0,0);
        acc = __builtin_amdgcn_mfma_f32_32x32x16_bf16(al, bh, acc, 0,0,0);
    }
    {
        const int n = lane & 31, mhl = (lane >> 5) << 2;
        #pragma unroll
        for (int reg = 0; reg < 16; ++reg) {
            const int mrow = (reg & 3) + 8*(reg >> 2) + mhl;
            part[wave][mrow][n] = acc[reg];
        }
    }
    __syncthreads();

    for (int i = tid; i < 1024; i += 256) {
        const int lm = i >> 5, ln = i & 31;
        const float sum = part[0][lm][ln] + part[1][lm][ln]
                        + part[2][lm][ln] + part[3][lm][ln];
        const int ch = bn + ln;
        const float val = fmaxf(fmaf(sf2[ch], sum, cf2[ch]), 0.f);
        const size_t o = (size_t)(bm + lm)*256 + ch;
        f2out[o] = val;
        const unsigned short hi = bf16r(val);
        f2h[o] = hi;
        f2l[o] = bf16r(val - bf2f(hi));
    }
}

// ---------------------------------------------------------------------------
// k_fc3m: fc3 via bf16x3 MFMA.  grid (8,25); 4 waves split K=256 (4 kt each);
// epilogue sum + bias -> C fp32 (no BN/relu, final layer).
// ---------------------------------------------------------------------------
__global__ __launch_bounds__(256) void k_fc3m(
    const unsigned short* __restrict__ f2h,  // [256][256]
    const unsigned short* __restrict__ f2l,
    const unsigned short* __restrict__ B3h,  // [16][25][64][8]
    const unsigned short* __restrict__ B3l,
    const float* __restrict__ bias,          // bf3 [800]
    float* __restrict__ C)                   // [256][800]
{
    __shared__ float part[4][32][33];

    const int tid = threadIdx.x;
    const int bm = blockIdx.x * 32;
    const int wave = tid >> 6, lane = tid & 63;
    const int m = bm + (lane & 31);
    const int kgrp = (lane >> 5) << 3;

    f32x16 acc = {0.f,0.f,0.f,0.f,0.f,0.f,0.f,0.f,
                  0.f,0.f,0.f,0.f,0.f,0.f,0.f,0.f};

    for (int kt = wave*4; kt < wave*4 + 4; ++kt) {
        const int kb = kt*16 + kgrp;
        const short8v ah = *(const short8v*)(f2h + (size_t)m*256 + kb);
        const short8v al = *(const short8v*)(f2l + (size_t)m*256 + kb);
        const size_t boff = (((size_t)kt*25 + blockIdx.y)*64 + lane) * 8;
        const short8v bh = *(const short8v*)(B3h + boff);
        const short8v bl = *(const short8v*)(B3l + boff);
        acc = __builtin_amdgcn_mfma_f32_32x32x16_bf16(ah, bh, acc, 0,0,0);
        acc = __builtin_amdgcn_mfma_f32_32x32x16_bf16(ah, bl, acc, 0,0,0);
        acc = __builtin_amdgcn_mfma_f32_32x32x16_bf16(al, bh, acc, 0,0,0);
    }
    {
        const int n = lane & 31, mhl = (lane >> 5) << 2;
        #pragma unroll
        for (int reg = 0; reg < 16; ++reg) {
            const int mrow = (reg & 3) + 8*(reg >> 2) + mhl;
            part[wave][mrow][n] = acc[reg];
        }
    }
    __syncthreads();

    for (int i = tid; i < 1024; i += 256) {
        const int lm = i >> 5, ln = i & 31;
        const float sum = part[0][lm][ln] + part[1][lm][ln]
                        + part[2][lm][ln] + part[3][lm][ln];
        const int ch = blockIdx.y * 32 + ln;             // < 800
        C[(size_t)(bm + lm)*800 + ch] = sum + bias[ch];
    }
}

// ---------------------------------------------------------------------------
extern "C" void kernel_launch(void* const* d_in, const int* in_sizes, int n_in,
                              void* d_out, int out_size, void* d_ws, size_t ws_size,
                              hipStream_t stream)
{
    const float* pts     = (const float*)d_in[0];
    const float* info    = (const float*)d_in[2];
    const float* w_info  = (const float*)d_in[3];
    const float* b_info  = (const float*)d_in[4];
    const float* g_info  = (const float*)d_in[5];
    const float* be_info = (const float*)d_in[6];
    const float* m_info  = (const float*)d_in[7];
    const float* v_info  = (const float*)d_in[8];
    const float* w2      = (const float*)d_in[9];
    const float* b2      = (const float*)d_in[10];
    const float* g2      = (const float*)d_in[11];
    const float* be2     = (const float*)d_in[12];
    const float* m2      = (const float*)d_in[13];
    const float* v2      = (const float*)d_in[14];
    const float* w3      = (const float*)d_in[15];
    const float* b3      = (const float*)d_in[16];
    const float* g3      = (const float*)d_in[17];
    const float* be3     = (const float*)d_in[18];
    const float* m3      = (const float*)d_in[19];
    const float* v3      = (const float*)d_in[20];
    const float* wf1     = (const float*)d_in[21];
    const float* bf1     = (const float*)d_in[22];
    const float* gf1     = (const float*)d_in[23];
    const float* bef1    = (const float*)d_in[24];
    const float* mf1     = (const float*)d_in[25];
    const float* vf1     = (const float*)d_in[26];
    const float* wf2     = (const float*)d_in[27];
    const float* bf2     = (const float*)d_in[28];
    const float* gf2     = (const float*)d_in[29];
    const float* bef2    = (const float*)d_in[30];
    const float* mf2     = (const float*)d_in[31];
    const float* vf2     = (const float*)d_in[32];
    const float* wf3     = (const float*)d_in[33];
    const float* bf3     = (const float*)d_in[34];

    float* ws = (float*)d_ws;
    // fc-MFMA region (float-slots = shorts/2):
    //   ghi [0..131072) glo [131072..262144)        edgeS3 -> fc1m
    //   f2h [0..32768)  f2l [32768..65536)          fc2m -> fc3m (over dead ghi)
    //   f1h [262144..327680) f1l [327680..393216)   fc1m -> fc2m
    //   B1h [393216..655360) B1l [655360..917504)
    //   B2h [917504..983040) B2l [983040..1048576)
    //   B3h [1048576..1150976) B3l [1150976..1253376)  (< 1277952 OK)
    unsigned short* ghi   = (unsigned short*)(ws + 0);
    unsigned short* glo   = (unsigned short*)(ws + 131072);
    unsigned short* f2h   = (unsigned short*)(ws + 0);        // reuse dead ghi
    unsigned short* f2l   = (unsigned short*)(ws + 32768);
    unsigned short* f1h   = (unsigned short*)(ws + 262144);
    unsigned short* f1l   = (unsigned short*)(ws + 327680);
    unsigned short* B1h   = (unsigned short*)(ws + 393216);
    unsigned short* B1l   = (unsigned short*)(ws + 655360);
    unsigned short* B2h   = (unsigned short*)(ws + 917504);
    unsigned short* B2l   = (unsigned short*)(ws + 983040);
    unsigned short* B3h   = (unsigned short*)(ws + 1048576);
    unsigned short* B3l   = (unsigned short*)(ws + 1150976);
    // constants region (unchanged offsets):
    unsigned short* Bh    = (unsigned short*)(ws + 1277952);
    unsigned short* Bl    = (unsigned short*)(ws + 1343488);
    float*          bias3 = ws + 1409024;
    float4*         w2q   = (float4*)(ws + 1410048);
    float*          bias2 = ws + 1418240;
    float4*         qTab4 = (float4*)(ws + 1418624);
    float*          sf1   = ws + 1418880;
    float*          cf1   = ws + 1419392;
    float*          sf2   = ws + 1419904;
    float*          cf2   = ws + 1420160;
    unsigned short* Bedge = (unsigned short*)(ws + 1420416);

    float* ret = (float*)d_out;            // [256, 800]
    float* f2  = ret + 256 * 800;          // [256, 256]

    k_pre<<<486, 256, 0, stream>>>(
        w3, b3, g3, be3, m3, v3,
        w2, b2, g2, be2, m2, v2,
        w_info, b_info, g_info, be_info, m_info, v_info,
        bf1, gf1, bef1, mf1, vf1,
        bf2, gf2, bef2, mf2, vf2,
        wf1, wf2, wf3,
        Bh, Bl, bias3, w2q, bias2, Bedge, qTab4, sf1, cf1, sf2, cf2,
        B1h, B1l, B2h, B2l, B3h, B3l);

    k_edgeS3<<<256, 512, 0, stream>>>(pts, info, Bedge, qTab4,
                                      w2q, bias2, Bh, Bl, bias3, ghi, glo);

    k_fc1m<<<dim3(8, 16), 256, 0, stream>>>(ghi, glo, B1h, B1l,
                                            sf1, cf1, f1h, f1l);

    k_fc2m<<<dim3(8, 8), 256, 0, stream>>>(f1h, f1l, B2h, B2l,
                                           sf2, cf2, f2, f2h, f2l);

    k_fc3m<<<dim3(8, 25), 256, 0, stream>>>(f2h, f2l, B3h, B3l, bf3, ret);
}